// Round 2
// baseline (8602.678 us; speedup 1.0000x reference)
//
#include <hip/hip_runtime.h>

// Problem constants (from reference)
constexpr int N  = 50000;
constexpr int E  = 300000;
constexpr int B  = 8;
constexpr int XD = 160;
constexpr int ED = 16;
constexpr int H  = 256;
constexpr int L  = 4;
constexpr int G  = 32;

// ---------------------------------------------------------------------------
// Kernel 0a: fuse edge-encoder layer-2 weights into per-layer message weights
//   we2[l] = ee_w2 @ msge_w[l]   [L,H,H]
// block = (l, row t); thread j computes we2[l][t][j] = sum_k ee_w2[t][k]*msge_w[l][k][j]
// ---------------------------------------------------------------------------
__global__ __launch_bounds__(256) void fuse_w_kernel(
    const float* __restrict__ ee_w2, const float* __restrict__ msge_w,
    float* __restrict__ we2)
{
    __shared__ float wrow[H];
    const int tid = threadIdx.x;
    const int l = blockIdx.x / H;
    const int t = blockIdx.x % H;
    wrow[tid] = ee_w2[t * H + tid];
    __syncthreads();
    const float* mw = msge_w + (size_t)l * H * H;
    float acc = 0.f;
    for (int k = 0; k < H; ++k)
        acc += wrow[k] * mw[k * H + tid];
    we2[((size_t)l * H + t) * H + tid] = acc;
}

// Kernel 0b: be2[l] = ee_b2 @ msge_w[l]   [L,H]
__global__ __launch_bounds__(256) void fuse_b_kernel(
    const float* __restrict__ ee_b2, const float* __restrict__ msge_w,
    float* __restrict__ be2)
{
    __shared__ float brow[H];
    const int tid = threadIdx.x;
    const int l = blockIdx.x;
    brow[tid] = ee_b2[tid];
    __syncthreads();
    const float* mw = msge_w + (size_t)l * H * H;
    float acc = 0.f;
    for (int k = 0; k < H; ++k)
        acc += brow[k] * mw[k * H + tid];
    be2[l * H + tid] = acc;
}

// ---------------------------------------------------------------------------
// Kernel 1: node input encoder
//   geo = relu(x[:, :128] @ geo_w + geo_b)            [N,32]
//   xin = concat(geo, x[:,128:])                      [N,64]
//   h   = relu(xin @ nin_w1 + b1) @ nin_w2 + b2       [N,256]
// 8 nodes per block, 256 threads.
// ---------------------------------------------------------------------------
__global__ __launch_bounds__(256) void node_in_kernel(
    const float* __restrict__ x,
    const float* __restrict__ geo_w, const float* __restrict__ geo_b,
    const float* __restrict__ w1, const float* __restrict__ b1,
    const float* __restrict__ w2, const float* __restrict__ b2,
    float* __restrict__ h)
{
    constexpr int NPB = 8;
    __shared__ __align__(16) float xrow[NPB][XD];
    __shared__ __align__(16) float xin[NPB][64];
    __shared__ __align__(16) float hid[NPB][H];
    const int tid = threadIdx.x;
    const int n0 = blockIdx.x * NPB;

    for (int i = tid; i < NPB * XD; i += 256) {
        int n = i / XD, k = i % XD;
        xrow[n][k] = x[(size_t)(n0 + n) * XD + k];
    }
    __syncthreads();

    // geo projection: 8 nodes x 32 outputs = 256 tasks
    {
        int n = tid >> 5, g = tid & 31;
        float acc = geo_b[g];
        for (int k = 0; k < 128; ++k)
            acc += xrow[n][k] * geo_w[k * G + g];
        xin[n][g] = fmaxf(acc, 0.f);
    }
    for (int i = tid; i < NPB * 32; i += 256) {
        int n = i >> 5, j = i & 31;
        xin[n][32 + j] = xrow[n][128 + j];
    }
    __syncthreads();

    // layer 1: 64 -> 256
    {
        float acc[NPB];
        #pragma unroll
        for (int n = 0; n < NPB; ++n) acc[n] = 0.f;
        for (int k = 0; k < 64; ++k) {
            float w = w1[k * H + tid];
            #pragma unroll
            for (int n = 0; n < NPB; ++n) acc[n] += xin[n][k] * w;
        }
        float bb = b1[tid];
        #pragma unroll
        for (int n = 0; n < NPB; ++n) hid[n][tid] = fmaxf(acc[n] + bb, 0.f);
    }
    __syncthreads();

    // layer 2: 256 -> 256
    {
        float acc[NPB];
        #pragma unroll
        for (int n = 0; n < NPB; ++n) acc[n] = 0.f;
        for (int k4 = 0; k4 < H / 4; ++k4) {
            int k = k4 * 4;
            float wa = w2[(k + 0) * H + tid];
            float wb = w2[(k + 1) * H + tid];
            float wc = w2[(k + 2) * H + tid];
            float wd = w2[(k + 3) * H + tid];
            #pragma unroll
            for (int n = 0; n < NPB; ++n) {
                float4 hv = *(const float4*)&hid[n][k];
                acc[n] += hv.x * wa + hv.y * wb + hv.z * wc + hv.w * wd;
            }
        }
        float bb = b2[tid];
        #pragma unroll
        for (int n = 0; n < NPB; ++n)
            h[(size_t)(n0 + n) * H + tid] = acc[n] + bb;
    }
}

// ---------------------------------------------------------------------------
// Kernel 3 (per layer): recompute edge hidden from raw ea, then
//   m = h[src] @ wx + hidden @ we2 + be2 ; atomic scatter-add to agg
// 16 edges per block.
// ---------------------------------------------------------------------------
__global__ __launch_bounds__(256) void msg2_kernel(
    const float* __restrict__ h, const float* __restrict__ ea,
    const float* __restrict__ ew1, const float* __restrict__ eb1,
    const float* __restrict__ wx, const float* __restrict__ we2,
    const float* __restrict__ be2,
    const int* __restrict__ src, const int* __restrict__ dst,
    float* __restrict__ agg)
{
    constexpr int EPB = 16;
    __shared__ __align__(16) float eat[EPB][ED];
    __shared__ __align__(16) float hs[EPB][H];
    __shared__ __align__(16) float hid[EPB][H];
    const int tid = threadIdx.x;
    const int e0 = blockIdx.x * EPB;

    // stage ea tile: 16x16 = 256 elements, one per thread
    {
        int j = tid >> 4, k = tid & 15;
        eat[j][k] = ea[(size_t)(e0 + j) * ED + k];
    }
    // stage h[src] tile
    #pragma unroll
    for (int j = 0; j < EPB; ++j) {
        int s = src[e0 + j];
        hs[j][tid] = h[(size_t)s * H + tid];
    }
    __syncthreads();

    // hidden = relu(ea @ ew1 + eb1): thread owns output column `tid`
    {
        float wv[ED];
        #pragma unroll
        for (int k = 0; k < ED; ++k) wv[k] = ew1[k * H + tid];
        float bb = eb1[tid];
        #pragma unroll
        for (int j = 0; j < EPB; ++j) {
            float acc = bb;
            #pragma unroll
            for (int k = 0; k < ED; ++k) acc += eat[j][k] * wv[k];
            hid[j][tid] = fmaxf(acc, 0.f);
        }
    }
    __syncthreads();

    float acc[EPB];
    {
        float bb = be2[tid];
        #pragma unroll
        for (int j = 0; j < EPB; ++j) acc[j] = bb;
    }

    for (int k4 = 0; k4 < H / 4; ++k4) {
        int k = k4 * 4;
        float ax0 = wx[(k + 0) * H + tid];
        float ax1 = wx[(k + 1) * H + tid];
        float ax2 = wx[(k + 2) * H + tid];
        float ax3 = wx[(k + 3) * H + tid];
        float ae0 = we2[(k + 0) * H + tid];
        float ae1 = we2[(k + 1) * H + tid];
        float ae2 = we2[(k + 2) * H + tid];
        float ae3 = we2[(k + 3) * H + tid];
        #pragma unroll
        for (int j = 0; j < EPB; ++j) {
            float4 hv = *(const float4*)&hs[j][k];
            float4 ev = *(const float4*)&hid[j][k];
            acc[j] += hv.x * ax0 + hv.y * ax1 + hv.z * ax2 + hv.w * ax3
                    + ev.x * ae0 + ev.y * ae1 + ev.z * ae2 + ev.w * ae3;
        }
    }

    #pragma unroll
    for (int j = 0; j < EPB; ++j)
        atomicAdd(&agg[(size_t)dst[e0 + j] * H + tid], acc[j]);
}

// ---------------------------------------------------------------------------
// Kernel 4 (per layer): u = relu(agg@w1+b1)@w2+b2 ; h = LN(h+u)
// 8 nodes per block.
// ---------------------------------------------------------------------------
__global__ __launch_bounds__(256) void upd_kernel(
    const float* __restrict__ agg,
    const float* __restrict__ w1, const float* __restrict__ b1,
    const float* __restrict__ w2, const float* __restrict__ b2,
    const float* __restrict__ lng, const float* __restrict__ lnb,
    float* __restrict__ h)
{
    constexpr int NPB = 8;
    __shared__ __align__(16) float a[NPB][H];
    __shared__ __align__(16) float hid[NPB][H];
    __shared__ float mu_s[NPB], rs_s[NPB];
    const int tid = threadIdx.x;
    const int n0 = blockIdx.x * NPB;

    #pragma unroll
    for (int j = 0; j < NPB; ++j)
        a[j][tid] = agg[(size_t)(n0 + j) * H + tid];
    __syncthreads();

    // layer 1
    {
        float acc[NPB];
        #pragma unroll
        for (int j = 0; j < NPB; ++j) acc[j] = 0.f;
        for (int k4 = 0; k4 < H / 4; ++k4) {
            int k = k4 * 4;
            float wa = w1[(k + 0) * H + tid];
            float wb = w1[(k + 1) * H + tid];
            float wc = w1[(k + 2) * H + tid];
            float wd = w1[(k + 3) * H + tid];
            #pragma unroll
            for (int j = 0; j < NPB; ++j) {
                float4 hv = *(const float4*)&a[j][k];
                acc[j] += hv.x * wa + hv.y * wb + hv.z * wc + hv.w * wd;
            }
        }
        float bb = b1[tid];
        #pragma unroll
        for (int j = 0; j < NPB; ++j) hid[j][tid] = fmaxf(acc[j] + bb, 0.f);
    }
    __syncthreads();

    // layer 2 + residual
    float vals[NPB];
    {
        float acc[NPB];
        #pragma unroll
        for (int j = 0; j < NPB; ++j) acc[j] = 0.f;
        for (int k4 = 0; k4 < H / 4; ++k4) {
            int k = k4 * 4;
            float wa = w2[(k + 0) * H + tid];
            float wb = w2[(k + 1) * H + tid];
            float wc = w2[(k + 2) * H + tid];
            float wd = w2[(k + 3) * H + tid];
            #pragma unroll
            for (int j = 0; j < NPB; ++j) {
                float4 hv = *(const float4*)&hid[j][k];
                acc[j] += hv.x * wa + hv.y * wb + hv.z * wc + hv.w * wd;
            }
        }
        float bb = b2[tid];
        #pragma unroll
        for (int j = 0; j < NPB; ++j)
            vals[j] = h[(size_t)(n0 + j) * H + tid] + acc[j] + bb;
    }
    __syncthreads();
    #pragma unroll
    for (int j = 0; j < NPB; ++j) a[j][tid] = vals[j];
    __syncthreads();

    // LayerNorm stats: 4 waves, each handles 2 rows
    {
        int wave = tid >> 6, lane = tid & 63;
        for (int r = wave; r < NPB; r += 4) {
            float s = a[r][lane] + a[r][lane + 64] + a[r][lane + 128] + a[r][lane + 192];
            for (int off = 32; off > 0; off >>= 1) s += __shfl_down(s, off, 64);
            float mu = __shfl(s, 0, 64) * (1.f / H);
            float d0 = a[r][lane] - mu, d1 = a[r][lane + 64] - mu;
            float d2 = a[r][lane + 128] - mu, d3 = a[r][lane + 192] - mu;
            float v = d0 * d0 + d1 * d1 + d2 * d2 + d3 * d3;
            for (int off = 32; off > 0; off >>= 1) v += __shfl_down(v, off, 64);
            v = __shfl(v, 0, 64) * (1.f / H);
            if (lane == 0) { mu_s[r] = mu; rs_s[r] = rsqrtf(v + 1e-5f); }
        }
    }
    __syncthreads();

    float g = lng[tid], bb2 = lnb[tid];
    #pragma unroll
    for (int j = 0; j < NPB; ++j)
        h[(size_t)(n0 + j) * H + tid] = (a[j][tid] - mu_s[j]) * rs_s[j] * g + bb2;
}

// ---------------------------------------------------------------------------
// Kernel 5: pooling partial sums. batch is sorted, so accumulate in LDS and
// flush on batch change. 256 nodes per block.
// ---------------------------------------------------------------------------
__global__ __launch_bounds__(256) void pool_kernel(
    const float* __restrict__ h, const int* __restrict__ batch,
    const int* __restrict__ ntype,
    float* __restrict__ zsum, float* __restrict__ zcnt)
{
    constexpr int CHUNK = 256;
    __shared__ float acc[3][H];
    __shared__ float cnt[3];
    const int tid = threadIdx.x;
    const int n0 = blockIdx.x * CHUNK;
    const int nend = min(n0 + CHUNK, N);

    for (int q = 0; q < 3; ++q) acc[q][tid] = 0.f;
    if (tid == 0) { cnt[0] = 0.f; cnt[1] = 0.f; cnt[2] = 0.f; }
    __syncthreads();

    int cur = batch[n0];
    for (int n = n0; n < nend; ++n) {
        int b = batch[n];   // uniform across block (batch sorted, scalar index)
        int t = ntype[n];
        if (b != cur) {
            for (int q = 0; q < 3; ++q) {
                atomicAdd(&zsum[cur * (3 * H) + q * H + tid], acc[q][tid]);
                acc[q][tid] = 0.f;
            }
            if (tid == 0) {
                for (int q = 0; q < 3; ++q) { atomicAdd(&zcnt[cur * 3 + q], cnt[q]); cnt[q] = 0.f; }
            }
            cur = b;
        }
        acc[t][tid] += h[(size_t)n * H + tid];
        if (tid == 0) cnt[t] += 1.f;
    }
    for (int q = 0; q < 3; ++q)
        atomicAdd(&zsum[cur * (3 * H) + q * H + tid], acc[q][tid]);
    if (tid == 0)
        for (int q = 0; q < 3; ++q) atomicAdd(&zcnt[cur * 3 + q], cnt[q]);
}

__global__ __launch_bounds__(256) void finalize_kernel(
    const float* __restrict__ zsum, const float* __restrict__ zcnt,
    float* __restrict__ out)
{
    int idx = blockIdx.x * 256 + threadIdx.x;
    if (idx >= B * 3 * H) return;
    int b = idx / (3 * H);
    int c = idx % (3 * H);
    int t = c / H;
    float cn = zcnt[b * 3 + t];
    out[idx] = zsum[idx] / fmaxf(cn, 1.f);
}

__global__ __launch_bounds__(256) void batch_out_kernel(
    const int* __restrict__ batch, float* __restrict__ out)
{
    int idx = blockIdx.x * 256 + threadIdx.x;
    if (idx < N) out[idx] = (float)batch[idx];
}

// ---------------------------------------------------------------------------
extern "C" void kernel_launch(void* const* d_in, const int* in_sizes, int n_in,
                              void* d_out, int out_size, void* d_ws, size_t ws_size,
                              hipStream_t stream) {
    const float* x         = (const float*)d_in[0];
    const float* edge_attr = (const float*)d_in[1];
    const float* geo_w     = (const float*)d_in[2];
    const float* geo_b     = (const float*)d_in[3];
    const float* nin_w1    = (const float*)d_in[4];
    const float* nin_b1    = (const float*)d_in[5];
    const float* nin_w2    = (const float*)d_in[6];
    const float* nin_b2    = (const float*)d_in[7];
    const float* ee_w1     = (const float*)d_in[8];
    const float* ee_b1     = (const float*)d_in[9];
    const float* ee_w2     = (const float*)d_in[10];
    const float* ee_b2     = (const float*)d_in[11];
    const float* msgx_w    = (const float*)d_in[12];
    const float* msge_w    = (const float*)d_in[13];
    const float* upd_w1    = (const float*)d_in[14];
    const float* upd_b1    = (const float*)d_in[15];
    const float* upd_w2    = (const float*)d_in[16];
    const float* upd_b2    = (const float*)d_in[17];
    const float* ln_g      = (const float*)d_in[18];
    const float* ln_b      = (const float*)d_in[19];
    const int*   edge_index= (const int*)d_in[20];
    const int*   batch     = (const int*)d_in[21];
    const int*   node_type = (const int*)d_in[22];

    float* out  = (float*)d_out;
    float* h    = out + B * 3 * H;                 // h lives directly in d_out

    // Workspace layout (~52.5 MB total — fits a modest d_ws):
    float* agg  = (float*)d_ws;                    // [N, H]      51.2 MB
    float* we2  = agg + (size_t)N * H;             // [L, H, H]    1.05 MB
    float* be2  = we2 + (size_t)L * H * H;         // [L, H]
    float* zsum = be2 + (size_t)L * H;             // [B, 3H]
    float* zcnt = zsum + B * 3 * H;                // [B, 3]

    const int* src = edge_index;
    const int* dst = edge_index + E;

    fuse_w_kernel<<<L * H, 256, 0, stream>>>(ee_w2, msge_w, we2);
    fuse_b_kernel<<<L, 256, 0, stream>>>(ee_b2, msge_w, be2);
    node_in_kernel<<<N / 8, 256, 0, stream>>>(x, geo_w, geo_b,
                                              nin_w1, nin_b1, nin_w2, nin_b2, h);
    for (int l = 0; l < L; ++l) {
        hipMemsetAsync(agg, 0, (size_t)N * H * sizeof(float), stream);
        msg2_kernel<<<E / 16, 256, 0, stream>>>(h, edge_attr, ee_w1, ee_b1,
                                                msgx_w + (size_t)l * H * H,
                                                we2 + (size_t)l * H * H,
                                                be2 + (size_t)l * H,
                                                src, dst, agg);
        upd_kernel<<<N / 8, 256, 0, stream>>>(agg,
                                              upd_w1 + (size_t)l * H * H, upd_b1 + l * H,
                                              upd_w2 + (size_t)l * H * H, upd_b2 + l * H,
                                              ln_g + l * H, ln_b + l * H, h);
    }
    hipMemsetAsync(zsum, 0, (size_t)(B * 3 * H + B * 3) * sizeof(float), stream);
    pool_kernel<<<(N + 255) / 256, 256, 0, stream>>>(h, batch, node_type, zsum, zcnt);
    finalize_kernel<<<(B * 3 * H + 255) / 256, 256, 0, stream>>>(zsum, zcnt, out);
    batch_out_kernel<<<(N + 255) / 256, 256, 0, stream>>>(batch, out + B * 3 * H + (size_t)N * H);
}

// Round 3
// 2178.772 us; speedup vs baseline: 3.9484x; 3.9484x over previous
//
#include <hip/hip_runtime.h>

// Problem constants (from reference)
constexpr int N  = 50000;
constexpr int E  = 300000;
constexpr int B  = 8;
constexpr int XD = 160;
constexpr int ED = 16;
constexpr int H  = 256;
constexpr int L  = 4;
constexpr int G  = 32;

typedef __attribute__((ext_vector_type(8))) short short8;
typedef __attribute__((ext_vector_type(4))) float floatx4;

// f32 -> bf16 round-to-nearest-even
__device__ __forceinline__ short f2bf(float f) {
    union { float f; unsigned u; } v; v.f = f;
    unsigned r = (v.u + 0x7fffu + ((v.u >> 16) & 1u)) >> 16;
    return (short)r;
}

// ---------------------------------------------------------------------------
// Prep 0a: we2bt[l][n][k] = bf16( (ee_w2 @ msge_w[l])[k][n] )   [L,H,H] bf16
// block = (l, k-row t); thread j computes sum_m ee_w2[t][m]*msge_w[l][m][j]
// ---------------------------------------------------------------------------
__global__ __launch_bounds__(256) void fuse_wbt_kernel(
    const float* __restrict__ ee_w2, const float* __restrict__ msge_w,
    short* __restrict__ we2bt)
{
    __shared__ float wrow[H];
    const int tid = threadIdx.x;
    const int l = blockIdx.x / H;
    const int t = blockIdx.x % H;          // K index of fused matrix
    wrow[tid] = ee_w2[t * H + tid];
    __syncthreads();
    const float* mw = msge_w + (size_t)l * H * H;
    float acc = 0.f;
    for (int k = 0; k < H; ++k)
        acc += wrow[k] * mw[k * H + tid];
    // transposed bf16 store: [n=tid][k=t]
    we2bt[((size_t)l * H + tid) * H + t] = f2bf(acc);
}

// Prep 0b: be2[l] = ee_b2 @ msge_w[l]   [L,H] f32
__global__ __launch_bounds__(256) void fuse_b_kernel(
    const float* __restrict__ ee_b2, const float* __restrict__ msge_w,
    float* __restrict__ be2)
{
    __shared__ float brow[H];
    const int tid = threadIdx.x;
    const int l = blockIdx.x;
    brow[tid] = ee_b2[tid];
    __syncthreads();
    const float* mw = msge_w + (size_t)l * H * H;
    float acc = 0.f;
    for (int k = 0; k < H; ++k)
        acc += brow[k] * mw[k * H + tid];
    be2[l * H + tid] = acc;
}

// Prep 0c: generic [mat][K=256][N=256] f32 -> bt [mat][n][k] bf16
// grid.x = nmat*256 (mat, k); threads over n (coalesced read, scattered write)
__global__ __launch_bounds__(256) void conv_bt_kernel(
    const float* __restrict__ w, short* __restrict__ bt)
{
    int mat = blockIdx.x >> 8, k = blockIdx.x & 255, n = threadIdx.x;
    bt[((size_t)mat * H + n) * H + k] = f2bf(w[((size_t)mat * H + k) * H + n]);
}

// Prep 0d: ew1bt[n][k] bf16, k padded 16->32 with zeros
__global__ __launch_bounds__(256) void ew1bt_kernel(
    const float* __restrict__ ew1, short* __restrict__ out)
{
    for (int i = threadIdx.x; i < H * 32; i += 256) {
        int n = i >> 5, k = i & 31;
        float v = (k < ED) ? ew1[k * H + n] : 0.f;
        out[n * 32 + k] = f2bf(v);
    }
}

// ---------------------------------------------------------------------------
// Kernel 1: node input encoder (f32 VALU — small). Writes h f32 + h_bf bf16.
// ---------------------------------------------------------------------------
__global__ __launch_bounds__(256) void node_in_kernel(
    const float* __restrict__ x,
    const float* __restrict__ geo_w, const float* __restrict__ geo_b,
    const float* __restrict__ w1, const float* __restrict__ b1,
    const float* __restrict__ w2, const float* __restrict__ b2,
    float* __restrict__ h, short* __restrict__ h_bf)
{
    constexpr int NPB = 8;
    __shared__ __align__(16) float xrow[NPB][XD];
    __shared__ __align__(16) float xin[NPB][64];
    __shared__ __align__(16) float hid[NPB][H];
    const int tid = threadIdx.x;
    const int n0 = blockIdx.x * NPB;

    for (int i = tid; i < NPB * XD; i += 256) {
        int n = i / XD, k = i % XD;
        xrow[n][k] = x[(size_t)(n0 + n) * XD + k];
    }
    __syncthreads();

    {
        int n = tid >> 5, g = tid & 31;
        float acc = geo_b[g];
        for (int k = 0; k < 128; ++k)
            acc += xrow[n][k] * geo_w[k * G + g];
        xin[n][g] = fmaxf(acc, 0.f);
    }
    for (int i = tid; i < NPB * 32; i += 256) {
        int n = i >> 5, j = i & 31;
        xin[n][32 + j] = xrow[n][128 + j];
    }
    __syncthreads();

    {
        float acc[NPB];
        #pragma unroll
        for (int n = 0; n < NPB; ++n) acc[n] = 0.f;
        for (int k = 0; k < 64; ++k) {
            float w = w1[k * H + tid];
            #pragma unroll
            for (int n = 0; n < NPB; ++n) acc[n] += xin[n][k] * w;
        }
        float bb = b1[tid];
        #pragma unroll
        for (int n = 0; n < NPB; ++n) hid[n][tid] = fmaxf(acc[n] + bb, 0.f);
    }
    __syncthreads();

    {
        float acc[NPB];
        #pragma unroll
        for (int n = 0; n < NPB; ++n) acc[n] = 0.f;
        for (int k4 = 0; k4 < H / 4; ++k4) {
            int k = k4 * 4;
            float wa = w2[(k + 0) * H + tid];
            float wb = w2[(k + 1) * H + tid];
            float wc = w2[(k + 2) * H + tid];
            float wd = w2[(k + 3) * H + tid];
            #pragma unroll
            for (int n = 0; n < NPB; ++n) {
                float4 hv = *(const float4*)&hid[n][k];
                acc[n] += hv.x * wa + hv.y * wb + hv.z * wc + hv.w * wd;
            }
        }
        float bb = b2[tid];
        #pragma unroll
        for (int n = 0; n < NPB; ++n) {
            float v = acc[n] + bb;
            h[(size_t)(n0 + n) * H + tid] = v;
            h_bf[(size_t)(n0 + n) * H + tid] = f2bf(v);
        }
    }
}

// ---------------------------------------------------------------------------
// Kernel 3 (per layer, MFMA): m = h_bf[src]@WX + relu(ea@EW1+eb1)@WE2 + be2
// then atomicAdd rows into agg[dst]. M=64 edges/block, wave owns N=64 cols.
// ---------------------------------------------------------------------------
__global__ __launch_bounds__(256) void msg_mfma_kernel(
    const short* __restrict__ h_bf, const float* __restrict__ ea,
    const short* __restrict__ ew1bt, const float* __restrict__ eb1,
    const short* __restrict__ wxbt, const short* __restrict__ we2bt,
    const float* __restrict__ be2,
    const int* __restrict__ src, const int* __restrict__ dst,
    float* __restrict__ agg)
{
    constexpr int KP = H + 8;               // +8 bf16 pad -> balanced LDS banks
    __shared__ short A2[64 * KP];           // hidden, bf16, A-layout
    __shared__ short Aea[64 * 32];          // ea, bf16, K zero-padded to 32
    __shared__ int srcs[64], dsts[64];
    const int tid  = threadIdx.x;
    const int lane = tid & 63, wave = tid >> 6;
    const int quad = lane >> 4, lm = lane & 15;
    const int e0 = blockIdx.x * 64;
    const int ncol = wave * 64 + lm;

    if (tid < 64)       srcs[tid]      = (e0 + tid < E) ? src[e0 + tid] : 0;
    else if (tid < 128) dsts[tid - 64] = (e0 + tid - 64 < E) ? dst[e0 + tid - 64] : 0;

    for (int i = tid; i < 64 * 16; i += 256) {
        int e = i >> 4, k = i & 15;
        float v = (e0 + e < E) ? ea[(size_t)(e0 + e) * ED + k] : 0.f;
        Aea[e * 32 + k] = f2bf(v);
        Aea[e * 32 + 16 + k] = 0;
    }
    __syncthreads();

    // --- edge-hidden GEMM: one K=32 step (zero-padded), relu, write A2 ---
    {
        short8 a[4], b[4];
        #pragma unroll
        for (int mt = 0; mt < 4; ++mt)
            a[mt] = *(const short8*)&Aea[(mt * 16 + lm) * 32 + quad * 8];
        #pragma unroll
        for (int nt = 0; nt < 4; ++nt)
            b[nt] = *(const short8*)&ew1bt[(size_t)(ncol + nt * 16) * 32 + quad * 8];
        float bb[4];
        #pragma unroll
        for (int nt = 0; nt < 4; ++nt) bb[nt] = eb1[ncol + nt * 16];
        #pragma unroll
        for (int mt = 0; mt < 4; ++mt) {
            #pragma unroll
            for (int nt = 0; nt < 4; ++nt) {
                floatx4 z = {0.f, 0.f, 0.f, 0.f};
                floatx4 c = __builtin_amdgcn_mfma_f32_16x16x32_bf16(a[mt], b[nt], z, 0, 0, 0);
                int col = ncol + nt * 16;
                #pragma unroll
                for (int r = 0; r < 4; ++r) {
                    int row = mt * 16 + quad * 4 + r;
                    A2[row * KP + col] = f2bf(fmaxf(c[r] + bb[nt], 0.f));
                }
            }
        }
    }
    __syncthreads();

    // --- main GEMM: acc init with fused bias be2 ---
    floatx4 acc[4][4];
    #pragma unroll
    for (int nt = 0; nt < 4; ++nt) {
        float bb = be2[ncol + nt * 16];
        #pragma unroll
        for (int mt = 0; mt < 4; ++mt) {
            acc[mt][nt][0] = bb; acc[mt][nt][1] = bb;
            acc[mt][nt][2] = bb; acc[mt][nt][3] = bb;
        }
    }

    // phase 1: K=256 over gathered h_bf (A direct from global)
    const short* ap[4];
    #pragma unroll
    for (int mt = 0; mt < 4; ++mt)
        ap[mt] = h_bf + (size_t)srcs[mt * 16 + lm] * H + quad * 8;
    const short* bp[4];
    #pragma unroll
    for (int nt = 0; nt < 4; ++nt)
        bp[nt] = wxbt + (size_t)(ncol + nt * 16) * H + quad * 8;

    #pragma unroll
    for (int ks = 0; ks < 8; ++ks) {
        short8 a[4], b[4];
        #pragma unroll
        for (int mt = 0; mt < 4; ++mt) a[mt] = *(const short8*)(ap[mt] + ks * 32);
        #pragma unroll
        for (int nt = 0; nt < 4; ++nt) b[nt] = *(const short8*)(bp[nt] + ks * 32);
        #pragma unroll
        for (int mt = 0; mt < 4; ++mt)
            #pragma unroll
            for (int nt = 0; nt < 4; ++nt)
                acc[mt][nt] = __builtin_amdgcn_mfma_f32_16x16x32_bf16(a[mt], b[nt], acc[mt][nt], 0, 0, 0);
    }

    // phase 2: K=256 over hidden (A from LDS)
    #pragma unroll
    for (int nt = 0; nt < 4; ++nt)
        bp[nt] = we2bt + (size_t)(ncol + nt * 16) * H + quad * 8;
    #pragma unroll
    for (int ks = 0; ks < 8; ++ks) {
        short8 a[4], b[4];
        #pragma unroll
        for (int mt = 0; mt < 4; ++mt)
            a[mt] = *(const short8*)&A2[(mt * 16 + lm) * KP + ks * 32 + quad * 8];
        #pragma unroll
        for (int nt = 0; nt < 4; ++nt) b[nt] = *(const short8*)(bp[nt] + ks * 32);
        #pragma unroll
        for (int mt = 0; mt < 4; ++mt)
            #pragma unroll
            for (int nt = 0; nt < 4; ++nt)
                acc[mt][nt] = __builtin_amdgcn_mfma_f32_16x16x32_bf16(a[mt], b[nt], acc[mt][nt], 0, 0, 0);
    }

    // epilogue: scatter-add (C layout: col=lane&15, row=quad*4+r)
    #pragma unroll
    for (int mt = 0; mt < 4; ++mt) {
        #pragma unroll
        for (int r = 0; r < 4; ++r) {
            int row = mt * 16 + quad * 4 + r;
            if (e0 + row < E) {
                int d = dsts[row];
                float* dest = agg + (size_t)d * H + ncol;
                #pragma unroll
                for (int nt = 0; nt < 4; ++nt)
                    atomicAdd(dest + nt * 16, acc[mt][nt][r]);
            }
        }
    }
}

// ---------------------------------------------------------------------------
// Kernel 4 (per layer, MFMA): u = relu(agg@W1+b1)@W2+b2 ; h = LN(h+u)
// M=64 nodes/block; LN via shfl_xor partials. Writes h f32 + h_bf.
// ---------------------------------------------------------------------------
__global__ __launch_bounds__(256) void upd_mfma_kernel(
    const float* __restrict__ agg,
    const short* __restrict__ u1bt, const float* __restrict__ b1,
    const short* __restrict__ u2bt, const float* __restrict__ b2,
    const float* __restrict__ lng, const float* __restrict__ lnb,
    float* __restrict__ h, short* __restrict__ h_bf)
{
    constexpr int KP = H + 8;
    __shared__ short A[64 * KP];
    __shared__ float psum[64][4], psq[64][4];
    __shared__ float muS[64], rsS[64];
    const int tid  = threadIdx.x;
    const int lane = tid & 63, wave = tid >> 6;
    const int quad = lane >> 4, lm = lane & 15;
    const int n0 = blockIdx.x * 64;
    const int nvalid = min(64, N - n0);
    const int ncol = wave * 64 + lm;

    // stage agg -> bf16 A-layout
    for (int i = tid; i < 64 * H; i += 256) {
        int row = i >> 8, col = i & 255;
        float v = (row < nvalid) ? agg[(size_t)(n0 + row) * H + col] : 0.f;
        A[row * KP + col] = f2bf(v);
    }
    __syncthreads();

    // GEMM1 (bias init, relu)
    floatx4 c1[4][4];
    #pragma unroll
    for (int nt = 0; nt < 4; ++nt) {
        float bb = b1[ncol + nt * 16];
        #pragma unroll
        for (int mt = 0; mt < 4; ++mt) {
            c1[mt][nt][0] = bb; c1[mt][nt][1] = bb;
            c1[mt][nt][2] = bb; c1[mt][nt][3] = bb;
        }
    }
    {
        const short* bp[4];
        #pragma unroll
        for (int nt = 0; nt < 4; ++nt)
            bp[nt] = u1bt + (size_t)(ncol + nt * 16) * H + quad * 8;
        #pragma unroll
        for (int ks = 0; ks < 8; ++ks) {
            short8 a[4], b[4];
            #pragma unroll
            for (int mt = 0; mt < 4; ++mt)
                a[mt] = *(const short8*)&A[(mt * 16 + lm) * KP + ks * 32 + quad * 8];
            #pragma unroll
            for (int nt = 0; nt < 4; ++nt) b[nt] = *(const short8*)(bp[nt] + ks * 32);
            #pragma unroll
            for (int mt = 0; mt < 4; ++mt)
                #pragma unroll
                for (int nt = 0; nt < 4; ++nt)
                    c1[mt][nt] = __builtin_amdgcn_mfma_f32_16x16x32_bf16(a[mt], b[nt], c1[mt][nt], 0, 0, 0);
        }
    }
    __syncthreads();   // all waves done reading A
    #pragma unroll
    for (int mt = 0; mt < 4; ++mt)
        #pragma unroll
        for (int nt = 0; nt < 4; ++nt) {
            int col = ncol + nt * 16;
            #pragma unroll
            for (int r = 0; r < 4; ++r) {
                int row = mt * 16 + quad * 4 + r;
                A[row * KP + col] = f2bf(fmaxf(c1[mt][nt][r], 0.f));
            }
        }
    __syncthreads();

    // GEMM2 (bias init) + residual
    floatx4 c2[4][4];
    #pragma unroll
    for (int nt = 0; nt < 4; ++nt) {
        float bb = b2[ncol + nt * 16];
        #pragma unroll
        for (int mt = 0; mt < 4; ++mt) {
            c2[mt][nt][0] = bb; c2[mt][nt][1] = bb;
            c2[mt][nt][2] = bb; c2[mt][nt][3] = bb;
        }
    }
    {
        const short* bp[4];
        #pragma unroll
        for (int nt = 0; nt < 4; ++nt)
            bp[nt] = u2bt + (size_t)(ncol + nt * 16) * H + quad * 8;
        #pragma unroll
        for (int ks = 0; ks < 8; ++ks) {
            short8 a[4], b[4];
            #pragma unroll
            for (int mt = 0; mt < 4; ++mt)
                a[mt] = *(const short8*)&A[(mt * 16 + lm) * KP + ks * 32 + quad * 8];
            #pragma unroll
            for (int nt = 0; nt < 4; ++nt) b[nt] = *(const short8*)(bp[nt] + ks * 32);
            #pragma unroll
            for (int mt = 0; mt < 4; ++mt)
                #pragma unroll
                for (int nt = 0; nt < 4; ++nt)
                    c2[mt][nt] = __builtin_amdgcn_mfma_f32_16x16x32_bf16(a[mt], b[nt], c2[mt][nt], 0, 0, 0);
        }
    }
    // residual add (f32 from global)
    #pragma unroll
    for (int mt = 0; mt < 4; ++mt)
        #pragma unroll
        for (int r = 0; r < 4; ++r) {
            int row = mt * 16 + quad * 4 + r;
            if (row < nvalid) {
                #pragma unroll
                for (int nt = 0; nt < 4; ++nt)
                    c2[mt][nt][r] += h[(size_t)(n0 + row) * H + ncol + nt * 16];
            }
        }

    // LN partials: sum over this wave's 64 cols per row
    #pragma unroll
    for (int mt = 0; mt < 4; ++mt)
        #pragma unroll
        for (int r = 0; r < 4; ++r) {
            float s = 0.f, q = 0.f;
            #pragma unroll
            for (int nt = 0; nt < 4; ++nt) {
                float v = c2[mt][nt][r];
                s += v; q += v * v;
            }
            #pragma unroll
            for (int m = 1; m < 16; m <<= 1) {
                s += __shfl_xor(s, m, 64);
                q += __shfl_xor(q, m, 64);
            }
            if (lm == 0) {
                int row = mt * 16 + quad * 4 + r;
                psum[row][wave] = s;
                psq[row][wave]  = q;
            }
        }
    __syncthreads();
    if (tid < 64) {
        float s = psum[tid][0] + psum[tid][1] + psum[tid][2] + psum[tid][3];
        float q = psq[tid][0] + psq[tid][1] + psq[tid][2] + psq[tid][3];
        float mu = s * (1.f / H);
        float var = q * (1.f / H) - mu * mu;
        muS[tid] = mu;
        rsS[tid] = rsqrtf(fmaxf(var, 0.f) + 1e-5f);
    }
    __syncthreads();

    float g[4], bb[4];
    #pragma unroll
    for (int nt = 0; nt < 4; ++nt) {
        g[nt]  = lng[ncol + nt * 16];
        bb[nt] = lnb[ncol + nt * 16];
    }
    #pragma unroll
    for (int mt = 0; mt < 4; ++mt)
        #pragma unroll
        for (int r = 0; r < 4; ++r) {
            int row = mt * 16 + quad * 4 + r;
            if (row < nvalid) {
                float mu = muS[row], rs = rsS[row];
                #pragma unroll
                for (int nt = 0; nt < 4; ++nt) {
                    float o = (c2[mt][nt][r] - mu) * rs * g[nt] + bb[nt];
                    size_t off = (size_t)(n0 + row) * H + ncol + nt * 16;
                    h[off] = o;
                    h_bf[off] = f2bf(o);
                }
            }
        }
}

// ---------------------------------------------------------------------------
// Kernel 5: pooling (batch sorted -> LDS accumulate, flush on change)
// ---------------------------------------------------------------------------
__global__ __launch_bounds__(256) void pool_kernel(
    const float* __restrict__ h, const int* __restrict__ batch,
    const int* __restrict__ ntype,
    float* __restrict__ zsum, float* __restrict__ zcnt)
{
    constexpr int CHUNK = 256;
    __shared__ float acc[3][H];
    __shared__ float cnt[3];
    const int tid = threadIdx.x;
    const int n0 = blockIdx.x * CHUNK;
    const int nend = min(n0 + CHUNK, N);

    for (int q = 0; q < 3; ++q) acc[q][tid] = 0.f;
    if (tid == 0) { cnt[0] = 0.f; cnt[1] = 0.f; cnt[2] = 0.f; }
    __syncthreads();

    int cur = batch[n0];
    for (int n = n0; n < nend; ++n) {
        int b = batch[n];
        int t = ntype[n];
        if (b != cur) {
            for (int q = 0; q < 3; ++q) {
                atomicAdd(&zsum[cur * (3 * H) + q * H + tid], acc[q][tid]);
                acc[q][tid] = 0.f;
            }
            if (tid == 0)
                for (int q = 0; q < 3; ++q) { atomicAdd(&zcnt[cur * 3 + q], cnt[q]); cnt[q] = 0.f; }
            cur = b;
        }
        acc[t][tid] += h[(size_t)n * H + tid];
        if (tid == 0) cnt[t] += 1.f;
    }
    for (int q = 0; q < 3; ++q)
        atomicAdd(&zsum[cur * (3 * H) + q * H + tid], acc[q][tid]);
    if (tid == 0)
        for (int q = 0; q < 3; ++q) atomicAdd(&zcnt[cur * 3 + q], cnt[q]);
}

__global__ __launch_bounds__(256) void finalize_kernel(
    const float* __restrict__ zsum, const float* __restrict__ zcnt,
    float* __restrict__ out)
{
    int idx = blockIdx.x * 256 + threadIdx.x;
    if (idx >= B * 3 * H) return;
    int b = idx / (3 * H);
    int c = idx % (3 * H);
    int t = c / H;
    float cn = zcnt[b * 3 + t];
    out[idx] = zsum[idx] / fmaxf(cn, 1.f);
}

__global__ __launch_bounds__(256) void batch_out_kernel(
    const int* __restrict__ batch, float* __restrict__ out)
{
    int idx = blockIdx.x * 256 + threadIdx.x;
    if (idx < N) out[idx] = (float)batch[idx];
}

// ---------------------------------------------------------------------------
extern "C" void kernel_launch(void* const* d_in, const int* in_sizes, int n_in,
                              void* d_out, int out_size, void* d_ws, size_t ws_size,
                              hipStream_t stream) {
    const float* x         = (const float*)d_in[0];
    const float* edge_attr = (const float*)d_in[1];
    const float* geo_w     = (const float*)d_in[2];
    const float* geo_b     = (const float*)d_in[3];
    const float* nin_w1    = (const float*)d_in[4];
    const float* nin_b1    = (const float*)d_in[5];
    const float* nin_w2    = (const float*)d_in[6];
    const float* nin_b2    = (const float*)d_in[7];
    const float* ee_w1     = (const float*)d_in[8];
    const float* ee_b1     = (const float*)d_in[9];
    const float* ee_w2     = (const float*)d_in[10];
    const float* ee_b2     = (const float*)d_in[11];
    const float* msgx_w    = (const float*)d_in[12];
    const float* msge_w    = (const float*)d_in[13];
    const float* upd_w1    = (const float*)d_in[14];
    const float* upd_b1    = (const float*)d_in[15];
    const float* upd_w2    = (const float*)d_in[16];
    const float* upd_b2    = (const float*)d_in[17];
    const float* ln_g      = (const float*)d_in[18];
    const float* ln_b      = (const float*)d_in[19];
    const int*   edge_index= (const int*)d_in[20];
    const int*   batch     = (const int*)d_in[21];
    const int*   node_type = (const int*)d_in[22];

    float* out  = (float*)d_out;
    float* h    = out + B * 3 * H;                 // h lives directly in d_out

    // Workspace layout (~79 MB):
    float* agg   = (float*)d_ws;                   // [N,H] f32      51.2 MB
    short* h_bf  = (short*)(agg + (size_t)N * H);  // [N,H] bf16     25.6 MB
    short* wxbt  = h_bf + (size_t)N * H;           // [L,H,H] bf16    0.52 MB
    short* we2bt = wxbt + (size_t)L * H * H;       // [L,H,H] bf16
    short* u1bt  = we2bt + (size_t)L * H * H;      // [L,H,H] bf16
    short* u2bt  = u1bt + (size_t)L * H * H;       // [L,H,H] bf16
    short* ew1bt = u2bt + (size_t)L * H * H;       // [H,32] bf16
    float* be2   = (float*)(ew1bt + H * 32);       // [L,H] f32
    float* zsum  = be2 + L * H;                    // [B,3H]
    float* zcnt  = zsum + B * 3 * H;               // [B,3]

    const int* src = edge_index;
    const int* dst = edge_index + E;

    // --- weight prep (cheap, once per launch) ---
    fuse_wbt_kernel<<<L * H, 256, 0, stream>>>(ee_w2, msge_w, we2bt);
    fuse_b_kernel<<<L, 256, 0, stream>>>(ee_b2, msge_w, be2);
    conv_bt_kernel<<<L * 256, 256, 0, stream>>>(msgx_w, wxbt);
    conv_bt_kernel<<<L * 256, 256, 0, stream>>>(upd_w1, u1bt);
    conv_bt_kernel<<<L * 256, 256, 0, stream>>>(upd_w2, u2bt);
    ew1bt_kernel<<<1, 256, 0, stream>>>(ee_w1, ew1bt);

    node_in_kernel<<<N / 8, 256, 0, stream>>>(x, geo_w, geo_b,
                                              nin_w1, nin_b1, nin_w2, nin_b2, h, h_bf);

    const int msg_grid = (E + 63) / 64;
    const int upd_grid = (N + 63) / 64;
    for (int l = 0; l < L; ++l) {
        hipMemsetAsync(agg, 0, (size_t)N * H * sizeof(float), stream);
        msg_mfma_kernel<<<msg_grid, 256, 0, stream>>>(h_bf, edge_attr, ew1bt, ee_b1,
                                                      wxbt + (size_t)l * H * H,
                                                      we2bt + (size_t)l * H * H,
                                                      be2 + (size_t)l * H,
                                                      src, dst, agg);
        upd_mfma_kernel<<<upd_grid, 256, 0, stream>>>(agg,
                                                      u1bt + (size_t)l * H * H, upd_b1 + l * H,
                                                      u2bt + (size_t)l * H * H, upd_b2 + l * H,
                                                      ln_g + l * H, ln_b + l * H, h, h_bf);
    }
    hipMemsetAsync(zsum, 0, (size_t)(B * 3 * H + B * 3) * sizeof(float), stream);
    pool_kernel<<<(N + 255) / 256, 256, 0, stream>>>(h, batch, node_type, zsum, zcnt);
    finalize_kernel<<<(B * 3 * H + 255) / 256, 256, 0, stream>>>(zsum, zcnt, out);
    batch_out_kernel<<<(N + 255) / 256, 256, 0, stream>>>(batch, out + B * 3 * H + (size_t)N * H);
}

// Round 5
// 1404.707 us; speedup vs baseline: 6.1242x; 1.5511x over previous
//
#include <hip/hip_runtime.h>

// Problem constants (from reference)
constexpr int N  = 50000;
constexpr int E  = 300000;
constexpr int B  = 8;
constexpr int XD = 160;
constexpr int ED = 16;
constexpr int H  = 256;
constexpr int L  = 4;
constexpr int G  = 32;

typedef __attribute__((ext_vector_type(8))) short short8;
typedef __attribute__((ext_vector_type(4))) short sv4;
typedef __attribute__((ext_vector_type(4))) float floatx4;

// f32 -> bf16 round-to-nearest-even
__device__ __forceinline__ short f2bf(float f) {
    union { float f; unsigned u; } v; v.f = f;
    unsigned r = (v.u + 0x7fffu + ((v.u >> 16) & 1u)) >> 16;
    return (short)r;
}

// ---------------------------------------------------------------------------
// CSR build: histogram, scan, fill
// ---------------------------------------------------------------------------
__global__ __launch_bounds__(256) void hist_kernel(
    const int* __restrict__ dst, int* __restrict__ cnt)
{
    int e = blockIdx.x * 256 + threadIdx.x;
    if (e < E) atomicAdd(&cnt[dst[e]], 1);
}

__global__ __launch_bounds__(256) void scan_kernel(
    const int* __restrict__ cnt, int* __restrict__ rs, int* __restrict__ cursor)
{
    __shared__ int s[256];
    __shared__ int carryS;
    const int tid = threadIdx.x;
    if (tid == 0) carryS = 0;
    __syncthreads();
    for (int t0 = 0; t0 < N; t0 += 256) {
        int v = (t0 + tid < N) ? cnt[t0 + tid] : 0;
        s[tid] = v;
        __syncthreads();
        #pragma unroll
        for (int off = 1; off < 256; off <<= 1) {
            int x = (tid >= off) ? s[tid - off] : 0;
            __syncthreads();
            s[tid] += x;
            __syncthreads();
        }
        int incl = s[tid];
        int excl = incl - v;
        int carry = carryS;
        if (t0 + tid < N) {
            rs[t0 + tid] = carry + excl;
            cursor[t0 + tid] = carry + excl;
        }
        __syncthreads();
        if (tid == 255) carryS = carry + incl;
        __syncthreads();
    }
    if (tid == 0) rs[N] = carryS;   // == E
}

__global__ __launch_bounds__(256) void fill_kernel(
    const int* __restrict__ src, const int* __restrict__ dst,
    int* __restrict__ cursor, int* __restrict__ csr_src, int* __restrict__ csr_eid)
{
    int e = blockIdx.x * 256 + threadIdx.x;
    if (e < E) {
        int d = dst[e];
        int pos = atomicAdd(&cursor[d], 1);
        csr_src[pos] = src[e];
        csr_eid[pos] = e;
    }
}

// ---------------------------------------------------------------------------
// hiddenAgg (once): haggB[d] = bf16( sum_{e: dst=d} relu(ea_e @ ee_w1 + ee_b1) )
// block = 64 dst nodes; wave w owns rows 16w..16w+15; lane owns cols 4*lane..+3
// ---------------------------------------------------------------------------
__global__ __launch_bounds__(256) void hidden_agg_kernel(
    const float* __restrict__ ea, const float* __restrict__ ew1,
    const float* __restrict__ eb1,
    const int* __restrict__ rs, const int* __restrict__ csr_eid,
    short* __restrict__ haggB)
{
    const int tid = threadIdx.x;
    const int lane = tid & 63, wave = tid >> 6;
    const int n0 = blockIdx.x * 64;

    // preload EW1 columns for this lane: w[k] = EW1[k][4*lane .. 4*lane+3]
    float4 w[ED];
    #pragma unroll
    for (int k = 0; k < ED; ++k)
        w[k] = *(const float4*)&ew1[k * H + 4 * lane];
    float4 bb = *(const float4*)&eb1[4 * lane];

    for (int t = 0; t < 16; ++t) {
        int n = n0 + wave * 16 + t;
        if (n >= N) continue;
        int s = rs[n], e = rs[n + 1];
        float4 acc = {0.f, 0.f, 0.f, 0.f};
        for (int j = s; j < e; ++j) {
            int eid = csr_eid[j];
            const float* ar = ea + (size_t)eid * ED;
            float4 hcol = bb;
            #pragma unroll
            for (int k = 0; k < ED; ++k) {
                float evk = ar[k];      // broadcast across lanes
                hcol.x += evk * w[k].x;
                hcol.y += evk * w[k].y;
                hcol.z += evk * w[k].z;
                hcol.w += evk * w[k].w;
            }
            acc.x += fmaxf(hcol.x, 0.f);
            acc.y += fmaxf(hcol.y, 0.f);
            acc.z += fmaxf(hcol.z, 0.f);
            acc.w += fmaxf(hcol.w, 0.f);
        }
        sv4 o = {f2bf(acc.x), f2bf(acc.y), f2bf(acc.z), f2bf(acc.w)};
        *(sv4*)&haggB[(size_t)n * H + 4 * lane] = o;
    }
}

// ---------------------------------------------------------------------------
// Weight prep
// ---------------------------------------------------------------------------
// wxwe[(l*H + n)*512 + k] : k<256 -> msgx_w[l][k][n]; k>=256 -> (ee_w2@msge_w[l])[k-256][n]
__global__ __launch_bounds__(256) void wx_part_kernel(
    const float* __restrict__ msgx_w, short* __restrict__ wxwe)
{
    int l = blockIdx.x >> 8, k = blockIdx.x & 255, n = threadIdx.x;
    wxwe[((size_t)(l * H + n)) * 512 + k] = f2bf(msgx_w[((size_t)l * H + k) * H + n]);
}

__global__ __launch_bounds__(256) void we_fuse_kernel(
    const float* __restrict__ ee_w2, const float* __restrict__ msge_w,
    short* __restrict__ wxwe)
{
    __shared__ float wrow[H];
    const int tid = threadIdx.x;
    const int l = blockIdx.x / H;
    const int t = blockIdx.x % H;          // K index of fused matrix
    wrow[tid] = ee_w2[t * H + tid];
    __syncthreads();
    const float* mw = msge_w + (size_t)l * H * H;
    float acc = 0.f;
    for (int k = 0; k < H; ++k)
        acc += wrow[k] * mw[k * H + tid];
    wxwe[((size_t)(l * H + tid)) * 512 + 256 + t] = f2bf(acc);
}

__global__ __launch_bounds__(256) void fuse_b_kernel(
    const float* __restrict__ ee_b2, const float* __restrict__ msge_w,
    float* __restrict__ be2)
{
    __shared__ float brow[H];
    const int tid = threadIdx.x;
    const int l = blockIdx.x;
    brow[tid] = ee_b2[tid];
    __syncthreads();
    const float* mw = msge_w + (size_t)l * H * H;
    float acc = 0.f;
    for (int k = 0; k < H; ++k)
        acc += brow[k] * mw[k * H + tid];
    be2[l * H + tid] = acc;
}

// generic [mat][K=256][N=256] f32 -> bt [mat][n][k] bf16
__global__ __launch_bounds__(256) void conv_bt_kernel(
    const float* __restrict__ w, short* __restrict__ bt)
{
    int mat = blockIdx.x >> 8, k = blockIdx.x & 255, n = threadIdx.x;
    bt[((size_t)mat * H + n) * H + k] = f2bf(w[((size_t)mat * H + k) * H + n]);
}

// geo_wbt[n=32][k=128] bf16 from geo_w[128][32]
__global__ __launch_bounds__(256) void geow_bt_kernel(
    const float* __restrict__ w, short* __restrict__ bt)
{
    for (int i = threadIdx.x; i < 32 * 128; i += 256) {
        int n = i >> 7, k = i & 127;
        bt[i] = f2bf(w[k * 32 + n]);
    }
}

// nin_w1bt[n=256][k=64] bf16 from nin_w1[64][256]
__global__ __launch_bounds__(256) void ninw1_bt_kernel(
    const float* __restrict__ w, short* __restrict__ bt)
{
    int i = blockIdx.x * 256 + threadIdx.x;   // grid 64 -> 16384
    int n = i >> 6, k = i & 63;
    bt[i] = f2bf(w[k * H + n]);
}

// ---------------------------------------------------------------------------
// Node input encoder (MFMA). M=64 nodes/block. Writes h f32.
// ---------------------------------------------------------------------------
__global__ __launch_bounds__(256) void node_in_mfma_kernel(
    const float* __restrict__ x,
    const short* __restrict__ geo_wbt, const float* __restrict__ geo_b,
    const short* __restrict__ w1bt, const float* __restrict__ b1,
    const short* __restrict__ w2bt, const float* __restrict__ b2,
    float* __restrict__ h)
{
    constexpr int KP = H + 8;      // hid stride (shorts)
    constexpr int KX = 128 + 8;    // Xg stride
    constexpr int KI = 64 + 8;     // xin stride
    __shared__ short A[64 * KP];
    __shared__ short XIN[64 * KI];
    const int tid = threadIdx.x;
    const int lane = tid & 63, wave = tid >> 6;
    const int quad = lane >> 4, lm = lane & 15;
    const int n0 = blockIdx.x * 64;
    const int nvalid = min(64, N - n0);
    const int ncol = wave * 64 + lm;

    for (int i = tid; i < 64 * 128; i += 256) {
        int row = i >> 7, k = i & 127;
        float v = (row < nvalid) ? x[(size_t)(n0 + row) * XD + k] : 0.f;
        A[row * KX + k] = f2bf(v);
    }
    for (int i = tid; i < 64 * 32; i += 256) {
        int row = i >> 5, k = i & 31;
        float v = (row < nvalid) ? x[(size_t)(n0 + row) * XD + 128 + k] : 0.f;
        XIN[row * KI + 32 + k] = f2bf(v);
    }
    __syncthreads();

    // geo GEMM: wave w owns rows w*16..w*16+15; N=32, K=128
    {
        floatx4 c[2];
        float b0 = geo_b[lm], b1v = geo_b[16 + lm];
        c[0] = {b0, b0, b0, b0};
        c[1] = {b1v, b1v, b1v, b1v};
        #pragma unroll
        for (int ks = 0; ks < 4; ++ks) {
            short8 a  = *(const short8*)&A[(wave * 16 + lm) * KX + ks * 32 + quad * 8];
            short8 w0 = *(const short8*)&geo_wbt[(size_t)lm * 128 + ks * 32 + quad * 8];
            short8 w1 = *(const short8*)&geo_wbt[(size_t)(16 + lm) * 128 + ks * 32 + quad * 8];
            c[0] = __builtin_amdgcn_mfma_f32_16x16x32_bf16(a, w0, c[0], 0, 0, 0);
            c[1] = __builtin_amdgcn_mfma_f32_16x16x32_bf16(a, w1, c[1], 0, 0, 0);
        }
        #pragma unroll
        for (int nt = 0; nt < 2; ++nt)
            #pragma unroll
            for (int r = 0; r < 4; ++r) {
                int row = wave * 16 + quad * 4 + r;
                XIN[row * KI + nt * 16 + lm] = f2bf(fmaxf(c[nt][r], 0.f));
            }
    }
    __syncthreads();

    // GEMM1: K=64 -> hid (relu) into A (stride KP)
    floatx4 c1[4][4];
    #pragma unroll
    for (int nt = 0; nt < 4; ++nt) {
        float bb = b1[ncol + nt * 16];
        #pragma unroll
        for (int mt = 0; mt < 4; ++mt) {
            c1[mt][nt][0] = bb; c1[mt][nt][1] = bb;
            c1[mt][nt][2] = bb; c1[mt][nt][3] = bb;
        }
    }
    #pragma unroll
    for (int ks = 0; ks < 2; ++ks) {
        short8 a[4], b[4];
        #pragma unroll
        for (int mt = 0; mt < 4; ++mt)
            a[mt] = *(const short8*)&XIN[(mt * 16 + lm) * KI + ks * 32 + quad * 8];
        #pragma unroll
        for (int nt = 0; nt < 4; ++nt)
            b[nt] = *(const short8*)&w1bt[(size_t)(ncol + nt * 16) * 64 + ks * 32 + quad * 8];
        #pragma unroll
        for (int mt = 0; mt < 4; ++mt)
            #pragma unroll
            for (int nt = 0; nt < 4; ++nt)
                c1[mt][nt] = __builtin_amdgcn_mfma_f32_16x16x32_bf16(a[mt], b[nt], c1[mt][nt], 0, 0, 0);
    }
    __syncthreads();
    #pragma unroll
    for (int mt = 0; mt < 4; ++mt)
        #pragma unroll
        for (int nt = 0; nt < 4; ++nt) {
            int col = ncol + nt * 16;
            #pragma unroll
            for (int r = 0; r < 4; ++r) {
                int row = mt * 16 + quad * 4 + r;
                A[row * KP + col] = f2bf(fmaxf(c1[mt][nt][r], 0.f));
            }
        }
    __syncthreads();

    // GEMM2: K=256 -> h
    floatx4 c2[4][4];
    #pragma unroll
    for (int nt = 0; nt < 4; ++nt) {
        float bb = b2[ncol + nt * 16];
        #pragma unroll
        for (int mt = 0; mt < 4; ++mt) {
            c2[mt][nt][0] = bb; c2[mt][nt][1] = bb;
            c2[mt][nt][2] = bb; c2[mt][nt][3] = bb;
        }
    }
    #pragma unroll
    for (int ks = 0; ks < 8; ++ks) {
        short8 a[4], b[4];
        #pragma unroll
        for (int mt = 0; mt < 4; ++mt)
            a[mt] = *(const short8*)&A[(mt * 16 + lm) * KP + ks * 32 + quad * 8];
        #pragma unroll
        for (int nt = 0; nt < 4; ++nt)
            b[nt] = *(const short8*)&w2bt[(size_t)(ncol + nt * 16) * H + ks * 32 + quad * 8];
        #pragma unroll
        for (int mt = 0; mt < 4; ++mt)
            #pragma unroll
            for (int nt = 0; nt < 4; ++nt)
                c2[mt][nt] = __builtin_amdgcn_mfma_f32_16x16x32_bf16(a[mt], b[nt], c2[mt][nt], 0, 0, 0);
    }
    #pragma unroll
    for (int mt = 0; mt < 4; ++mt)
        #pragma unroll
        for (int r = 0; r < 4; ++r) {
            int row = mt * 16 + quad * 4 + r;
            if (row < nvalid) {
                #pragma unroll
                for (int nt = 0; nt < 4; ++nt)
                    h[(size_t)(n0 + row) * H + ncol + nt * 16] = c2[mt][nt][r];
            }
        }
}

// ---------------------------------------------------------------------------
// Fused layer kernel (per layer): for 64 dst nodes,
//   hAgg = sum_{e in CSR} h_in[src]            (gather, no atomics)
//   agg  = [hAgg | hiddenAgg] @ [WX;WE2] (K=512) + deg*be2
//   u    = relu(agg@W1+b1)@W2+b2
//   h_out = LN(h_in + u)
// ---------------------------------------------------------------------------
__global__ __launch_bounds__(256) void layer_kernel(
    const float* __restrict__ h_in, float* __restrict__ h_out,
    const int* __restrict__ rs, const int* __restrict__ csr_src,
    const short* __restrict__ haggB,
    const short* __restrict__ wxwe, const float* __restrict__ be2,
    const short* __restrict__ u1bt, const float* __restrict__ b1,
    const short* __restrict__ u2bt, const float* __restrict__ b2,
    const float* __restrict__ lng, const float* __restrict__ lnb)
{
    constexpr int KP2 = 512 + 8;
    constexpr int KP  = H + 8;
    __shared__ short A[64 * KP2];
    __shared__ int rsL[65];
    __shared__ float psum[64][4], psq[64][4];
    __shared__ float muS[64], rsS[64];
    const int tid  = threadIdx.x;
    const int lane = tid & 63, wave = tid >> 6;
    const int quad = lane >> 4, lm = lane & 15;
    const int n0 = blockIdx.x * 64;
    const int nvalid = min(64, N - n0);
    const int ncol = wave * 64 + lm;

    if (tid < 65) rsL[tid] = rs[min(n0 + tid, N)];
    __syncthreads();

    // --- stage 1: gather hAgg rows (wave w owns rows 16w..16w+15) ---
    for (int t = 0; t < 16; ++t) {
        int row = wave * 16 + t;
        int s = rsL[row], e = rsL[row + 1];
        float4 acc = {0.f, 0.f, 0.f, 0.f};
        int j = s;
        for (; j + 1 < e; j += 2) {
            int s0 = csr_src[j], s1 = csr_src[j + 1];
            float4 v0 = *(const float4*)&h_in[(size_t)s0 * H + 4 * lane];
            float4 v1 = *(const float4*)&h_in[(size_t)s1 * H + 4 * lane];
            acc.x += v0.x + v1.x; acc.y += v0.y + v1.y;
            acc.z += v0.z + v1.z; acc.w += v0.w + v1.w;
        }
        if (j < e) {
            int s0 = csr_src[j];
            float4 v0 = *(const float4*)&h_in[(size_t)s0 * H + 4 * lane];
            acc.x += v0.x; acc.y += v0.y; acc.z += v0.z; acc.w += v0.w;
        }
        sv4 o = {f2bf(acc.x), f2bf(acc.y), f2bf(acc.z), f2bf(acc.w)};
        *(sv4*)&A[row * KP2 + 4 * lane] = o;
    }
    // --- stage 1b: hiddenAgg -> A cols 256..511 ---
    for (int i = tid; i < 64 * 64; i += 256) {
        int row = i >> 6, q = i & 63;
        sv4 v = {0, 0, 0, 0};
        if (row < nvalid)
            v = *(const sv4*)&haggB[(size_t)(n0 + row) * H + 4 * q];
        *(sv4*)&A[row * KP2 + 256 + 4 * q] = v;
    }
    __syncthreads();

    // --- stage 2: K=512 GEMM, acc init deg*be2 ---
    floatx4 c1[4][4];
    #pragma unroll
    for (int nt = 0; nt < 4; ++nt) {
        float bb = be2[ncol + nt * 16];
        #pragma unroll
        for (int mt = 0; mt < 4; ++mt) {
            #pragma unroll
            for (int r = 0; r < 4; ++r) {
                int row = mt * 16 + quad * 4 + r;
                float deg = (float)(rsL[row + 1] - rsL[row]);
                c1[mt][nt][r] = deg * bb;
            }
        }
    }
    #pragma unroll
    for (int ks = 0; ks < 16; ++ks) {
        short8 a[4], b[4];
        #pragma unroll
        for (int mt = 0; mt < 4; ++mt)
            a[mt] = *(const short8*)&A[(mt * 16 + lm) * KP2 + ks * 32 + quad * 8];
        #pragma unroll
        for (int nt = 0; nt < 4; ++nt)
            b[nt] = *(const short8*)&wxwe[(size_t)(ncol + nt * 16) * 512 + ks * 32 + quad * 8];
        #pragma unroll
        for (int mt = 0; mt < 4; ++mt)
            #pragma unroll
            for (int nt = 0; nt < 4; ++nt)
                c1[mt][nt] = __builtin_amdgcn_mfma_f32_16x16x32_bf16(a[mt], b[nt], c1[mt][nt], 0, 0, 0);
    }
    __syncthreads();
    // write agg (bf16) into A at stride KP
    #pragma unroll
    for (int mt = 0; mt < 4; ++mt)
        #pragma unroll
        for (int nt = 0; nt < 4; ++nt) {
            int col = ncol + nt * 16;
            #pragma unroll
            for (int r = 0; r < 4; ++r) {
                int row = mt * 16 + quad * 4 + r;
                A[row * KP + col] = f2bf(c1[mt][nt][r]);
            }
        }
    __syncthreads();

    // --- stage 3: GEMM K=256 @W1 + b1, relu -> A ---
    floatx4 c2[4][4];
    #pragma unroll
    for (int nt = 0; nt < 4; ++nt) {
        float bb = b1[ncol + nt * 16];
        #pragma unroll
        for (int mt = 0; mt < 4; ++mt) {
            c2[mt][nt][0] = bb; c2[mt][nt][1] = bb;
            c2[mt][nt][2] = bb; c2[mt][nt][3] = bb;
        }
    }
    #pragma unroll
    for (int ks = 0; ks < 8; ++ks) {
        short8 a[4], b[4];
        #pragma unroll
        for (int mt = 0; mt < 4; ++mt)
            a[mt] = *(const short8*)&A[(mt * 16 + lm) * KP + ks * 32 + quad * 8];
        #pragma unroll
        for (int nt = 0; nt < 4; ++nt)
            b[nt] = *(const short8*)&u1bt[(size_t)(ncol + nt * 16) * H + ks * 32 + quad * 8];
        #pragma unroll
        for (int mt = 0; mt < 4; ++mt)
            #pragma unroll
            for (int nt = 0; nt < 4; ++nt)
                c2[mt][nt] = __builtin_amdgcn_mfma_f32_16x16x32_bf16(a[mt], b[nt], c2[mt][nt], 0, 0, 0);
    }
    __syncthreads();
    #pragma unroll
    for (int mt = 0; mt < 4; ++mt)
        #pragma unroll
        for (int nt = 0; nt < 4; ++nt) {
            int col = ncol + nt * 16;
            #pragma unroll
            for (int r = 0; r < 4; ++r) {
                int row = mt * 16 + quad * 4 + r;
                A[row * KP + col] = f2bf(fmaxf(c2[mt][nt][r], 0.f));
            }
        }
    __syncthreads();

    // --- stage 4: GEMM K=256 @W2 + b2 + residual; LN; store ---
    floatx4 c3[4][4];
    #pragma unroll
    for (int nt = 0; nt < 4; ++nt) {
        float bb = b2[ncol + nt * 16];
        #pragma unroll
        for (int mt = 0; mt < 4; ++mt) {
            c3[mt][nt][0] = bb; c3[mt][nt][1] = bb;
            c3[mt][nt][2] = bb; c3[mt][nt][3] = bb;
        }
    }
    #pragma unroll
    for (int ks = 0; ks < 8; ++ks) {
        short8 a[4], b[4];
        #pragma unroll
        for (int mt = 0; mt < 4; ++mt)
            a[mt] = *(const short8*)&A[(mt * 16 + lm) * KP + ks * 32 + quad * 8];
        #pragma unroll
        for (int nt = 0; nt < 4; ++nt)
            b[nt] = *(const short8*)&u2bt[(size_t)(ncol + nt * 16) * H + ks * 32 + quad * 8];
        #pragma unroll
        for (int mt = 0; mt < 4; ++mt)
            #pragma unroll
            for (int nt = 0; nt < 4; ++nt)
                c3[mt][nt] = __builtin_amdgcn_mfma_f32_16x16x32_bf16(a[mt], b[nt], c3[mt][nt], 0, 0, 0);
    }
    #pragma unroll
    for (int mt = 0; mt < 4; ++mt)
        #pragma unroll
        for (int r = 0; r < 4; ++r) {
            int row = mt * 16 + quad * 4 + r;
            if (row < nvalid) {
                #pragma unroll
                for (int nt = 0; nt < 4; ++nt)
                    c3[mt][nt][r] += h_in[(size_t)(n0 + row) * H + ncol + nt * 16];
            }
        }

    // LN partials
    #pragma unroll
    for (int mt = 0; mt < 4; ++mt)
        #pragma unroll
        for (int r = 0; r < 4; ++r) {
            float s = 0.f, q = 0.f;
            #pragma unroll
            for (int nt = 0; nt < 4; ++nt) {
                float v = c3[mt][nt][r];
                s += v; q += v * v;
            }
            #pragma unroll
            for (int m = 1; m < 16; m <<= 1) {
                s += __shfl_xor(s, m, 64);
                q += __shfl_xor(q, m, 64);
            }
            if (lm == 0) {
                int row = mt * 16 + quad * 4 + r;
                psum[row][wave] = s;
                psq[row][wave]  = q;
            }
        }
    __syncthreads();
    if (tid < 64) {
        float s = psum[tid][0] + psum[tid][1] + psum[tid][2] + psum[tid][3];
        float q = psq[tid][0] + psq[tid][1] + psq[tid][2] + psq[tid][3];
        float mu = s * (1.f / H);
        float var = q * (1.f / H) - mu * mu;
        muS[tid] = mu;
        rsS[tid] = rsqrtf(fmaxf(var, 0.f) + 1e-5f);
    }
    __syncthreads();

    float g[4], bb4[4];
    #pragma unroll
    for (int nt = 0; nt < 4; ++nt) {
        g[nt]   = lng[ncol + nt * 16];
        bb4[nt] = lnb[ncol + nt * 16];
    }
    #pragma unroll
    for (int mt = 0; mt < 4; ++mt)
        #pragma unroll
        for (int r = 0; r < 4; ++r) {
            int row = mt * 16 + quad * 4 + r;
            if (row < nvalid) {
                float mu = muS[row], rsv = rsS[row];
                #pragma unroll
                for (int nt = 0; nt < 4; ++nt) {
                    float o = (c3[mt][nt][r] - mu) * rsv * g[nt] + bb4[nt];
                    h_out[(size_t)(n0 + row) * H + ncol + nt * 16] = o;
                }
            }
        }
}

// ---------------------------------------------------------------------------
// Pooling (batch sorted -> LDS accumulate, flush on change)
// ---------------------------------------------------------------------------
__global__ __launch_bounds__(256) void pool_kernel(
    const float* __restrict__ h, const int* __restrict__ batch,
    const int* __restrict__ ntype,
    float* __restrict__ zsum, float* __restrict__ zcnt)
{
    constexpr int CHUNK = 256;
    __shared__ float acc[3][H];
    __shared__ float cnt[3];
    const int tid = threadIdx.x;
    const int n0 = blockIdx.x * CHUNK;
    const int nend = min(n0 + CHUNK, N);

    for (int q = 0; q < 3; ++q) acc[q][tid] = 0.f;
    if (tid == 0) { cnt[0] = 0.f; cnt[1] = 0.f; cnt[2] = 0.f; }
    __syncthreads();

    int cur = batch[n0];
    for (int n = n0; n < nend; ++n) {
        int b = batch[n];
        int t = ntype[n];
        if (b != cur) {
            for (int q = 0; q < 3; ++q) {
                atomicAdd(&zsum[cur * (3 * H) + q * H + tid], acc[q][tid]);
                acc[q][tid] = 0.f;
            }
            if (tid == 0)
                for (int q = 0; q < 3; ++q) { atomicAdd(&zcnt[cur * 3 + q], cnt[q]); cnt[q] = 0.f; }
            cur = b;
        }
        acc[t][tid] += h[(size_t)n * H + tid];
        if (tid == 0) cnt[t] += 1.f;
    }
    for (int q = 0; q < 3; ++q)
        atomicAdd(&zsum[cur * (3 * H) + q * H + tid], acc[q][tid]);
    if (tid == 0)
        for (int q = 0; q < 3; ++q) atomicAdd(&zcnt[cur * 3 + q], cnt[q]);
}

__global__ __launch_bounds__(256) void finalize_kernel(
    const float* __restrict__ zsum, const float* __restrict__ zcnt,
    float* __restrict__ out)
{
    int idx = blockIdx.x * 256 + threadIdx.x;
    if (idx >= B * 3 * H) return;
    int b = idx / (3 * H);
    int c = idx % (3 * H);
    int t = c / H;
    float cn = zcnt[b * 3 + t];
    out[idx] = zsum[idx] / fmaxf(cn, 1.f);
}

__global__ __launch_bounds__(256) void batch_out_kernel(
    const int* __restrict__ batch, float* __restrict__ out)
{
    int idx = blockIdx.x * 256 + threadIdx.x;
    if (idx < N) out[idx] = (float)batch[idx];
}

// ---------------------------------------------------------------------------
extern "C" void kernel_launch(void* const* d_in, const int* in_sizes, int n_in,
                              void* d_out, int out_size, void* d_ws, size_t ws_size,
                              hipStream_t stream) {
    const float* x         = (const float*)d_in[0];
    const float* edge_attr = (const float*)d_in[1];
    const float* geo_w     = (const float*)d_in[2];
    const float* geo_b     = (const float*)d_in[3];
    const float* nin_w1    = (const float*)d_in[4];
    const float* nin_b1    = (const float*)d_in[5];
    const float* nin_w2    = (const float*)d_in[6];
    const float* nin_b2    = (const float*)d_in[7];
    const float* ee_w1     = (const float*)d_in[8];
    const float* ee_b1     = (const float*)d_in[9];
    const float* ee_w2     = (const float*)d_in[10];
    const float* ee_b2     = (const float*)d_in[11];
    const float* msgx_w    = (const float*)d_in[12];
    const float* msge_w    = (const float*)d_in[13];
    const float* upd_w1    = (const float*)d_in[14];
    const float* upd_b1    = (const float*)d_in[15];
    const float* upd_w2    = (const float*)d_in[16];
    const float* upd_b2    = (const float*)d_in[17];
    const float* ln_g      = (const float*)d_in[18];
    const float* ln_b      = (const float*)d_in[19];
    const int*   edge_index= (const int*)d_in[20];
    const int*   batch     = (const int*)d_in[21];
    const int*   node_type = (const int*)d_in[22];

    float* out = (float*)d_out;
    float* h0  = out + B * 3 * H;                  // final h lives in d_out

    // Workspace layout (~69 MB):
    float* h1      = (float*)d_ws;                     // [N,H] f32     51.2 MB
    short* haggB   = (short*)(h1 + (size_t)N * H);     // [N,H] bf16    25.6/2 MB
    short* wxwe    = haggB + (size_t)N * H;            // [L,H,512] bf16 1.05 MB
    short* u1bt    = wxwe + (size_t)L * H * 512;       // [L,H,H] bf16
    short* u2bt    = u1bt + (size_t)L * H * H;         // [L,H,H] bf16
    short* geowbt  = u2bt + (size_t)L * H * H;         // [32,128]
    short* w1bt    = geowbt + 32 * 128;                // [H,64]
    short* w2bt    = w1bt + H * 64;                    // [H,H]
    float* be2     = (float*)(w2bt + H * H);           // [L,H]
    float* zsum    = be2 + L * H;                      // [B,3H]
    float* zcnt    = zsum + B * 3 * H;                 // [B,3]
    int*   rowcnt  = (int*)(zcnt + B * 3);             // [N]
    int*   rs      = rowcnt + N;                       // [N+1]
    int*   cursor  = rs + N + 1;                       // [N]
    int*   csr_src = cursor + N;                       // [E]
    int*   csr_eid = csr_src + E;                      // [E]

    const int* src = edge_index;
    const int* dst = edge_index + E;

    // --- CSR build ---
    hipMemsetAsync(rowcnt, 0, (size_t)N * sizeof(int), stream);
    hist_kernel<<<(E + 255) / 256, 256, 0, stream>>>(dst, rowcnt);
    scan_kernel<<<1, 256, 0, stream>>>(rowcnt, rs, cursor);
    fill_kernel<<<(E + 255) / 256, 256, 0, stream>>>(src, dst, cursor, csr_src, csr_eid);

    // --- weight prep ---
    wx_part_kernel<<<L * 256, 256, 0, stream>>>(msgx_w, wxwe);
    we_fuse_kernel<<<L * H, 256, 0, stream>>>(ee_w2, msge_w, wxwe);
    fuse_b_kernel<<<L, 256, 0, stream>>>(ee_b2, msge_w, be2);
    conv_bt_kernel<<<L * 256, 256, 0, stream>>>(upd_w1, u1bt);
    conv_bt_kernel<<<L * 256, 256, 0, stream>>>(upd_w2, u2bt);
    conv_bt_kernel<<<256, 256, 0, stream>>>(nin_w2, w2bt);
    geow_bt_kernel<<<1, 256, 0, stream>>>(geo_w, geowbt);
    ninw1_bt_kernel<<<64, 256, 0, stream>>>(nin_w1, w1bt);

    // --- hiddenAgg (layer-independent) ---
    hidden_agg_kernel<<<(N + 63) / 64, 256, 0, stream>>>(
        edge_attr, ee_w1, ee_b1, rs, csr_eid, haggB);

    // --- node encoder -> h0 ---
    node_in_mfma_kernel<<<(N + 63) / 64, 256, 0, stream>>>(
        x, geowbt, geo_b, w1bt, nin_b1, w2bt, nin_b2, h0);

    // --- layers (ping-pong h0/h1, L=4 even -> ends in h0) ---
    const int lgrid = (N + 63) / 64;
    for (int l = 0; l < L; ++l) {
        const float* hin  = (l & 1) ? h1 : h0;
        float*       hout = (l & 1) ? h0 : h1;
        layer_kernel<<<lgrid, 256, 0, stream>>>(
            hin, hout, rs, csr_src, haggB,
            wxwe + (size_t)l * H * 512, be2 + (size_t)l * H,
            u1bt + (size_t)l * H * H, upd_b1 + (size_t)l * H,
            u2bt + (size_t)l * H * H, upd_b2 + (size_t)l * H,
            ln_g + (size_t)l * H, ln_b + (size_t)l * H);
    }

    // --- pooling ---
    hipMemsetAsync(zsum, 0, (size_t)(B * 3 * H + B * 3) * sizeof(float), stream);
    pool_kernel<<<(N + 255) / 256, 256, 0, stream>>>(h0, batch, node_type, zsum, zcnt);
    finalize_kernel<<<(B * 3 * H + 255) / 256, 256, 0, stream>>>(zsum, zcnt, out);
    batch_out_kernel<<<(N + 255) / 256, 256, 0, stream>>>(batch, out + B * 3 * H + (size_t)N * H);
}

// Round 6
// 1272.993 us; speedup vs baseline: 6.7578x; 1.1035x over previous
//
#include <hip/hip_runtime.h>

// Problem constants (from reference)
constexpr int N  = 50000;
constexpr int E  = 300000;
constexpr int B  = 8;
constexpr int XD = 160;
constexpr int ED = 16;
constexpr int H  = 256;
constexpr int L  = 4;
constexpr int G  = 32;

typedef __attribute__((ext_vector_type(8))) short short8;
typedef __attribute__((ext_vector_type(4))) short sv4;
typedef __attribute__((ext_vector_type(4))) float floatx4;

// f32 -> bf16 round-to-nearest-even
__device__ __forceinline__ short f2bf(float f) {
    union { float f; unsigned u; } v; v.f = f;
    unsigned r = (v.u + 0x7fffu + ((v.u >> 16) & 1u)) >> 16;
    return (short)r;
}
__device__ __forceinline__ float bf2f(short s) {
    union { unsigned u; float f; } v;
    v.u = ((unsigned)(unsigned short)s) << 16;
    return v.f;
}

// ---------------------------------------------------------------------------
// CSR build: histogram, 3-pass multi-block scan, fill
// ---------------------------------------------------------------------------
__global__ __launch_bounds__(256) void hist_kernel(
    const int* __restrict__ dst, int* __restrict__ cnt)
{
    int e = blockIdx.x * 256 + threadIdx.x;
    if (e < E) atomicAdd(&cnt[dst[e]], 1);
}

// pass A: per-block sums of cnt (256 elems/block)
__global__ __launch_bounds__(256) void scan_partial_kernel(
    const int* __restrict__ cnt, int* __restrict__ bsum)
{
    __shared__ int s[256];
    const int tid = threadIdx.x;
    int i = blockIdx.x * 256 + tid;
    s[tid] = (i < N) ? cnt[i] : 0;
    __syncthreads();
    #pragma unroll
    for (int off = 128; off > 0; off >>= 1) {
        if (tid < off) s[tid] += s[tid + off];
        __syncthreads();
    }
    if (tid == 0) bsum[blockIdx.x] = s[0];
}

// pass B: single block scans the <=256 block sums -> exclusive offsets; total -> rsN
__global__ __launch_bounds__(256) void scan_bsum_kernel(
    int* __restrict__ bsum, int nb, int* __restrict__ rsN)
{
    __shared__ int s[256];
    const int tid = threadIdx.x;
    int v = (tid < nb) ? bsum[tid] : 0;
    s[tid] = v;
    __syncthreads();
    #pragma unroll
    for (int off = 1; off < 256; off <<= 1) {
        int x = (tid >= off) ? s[tid - off] : 0;
        __syncthreads();
        s[tid] += x;
        __syncthreads();
    }
    if (tid < nb) bsum[tid] = s[tid] - v;    // exclusive
    if (tid == 255) *rsN = s[255];           // total == E
}

// pass C: local exclusive scan + block offset -> rs, cursor
__global__ __launch_bounds__(256) void scan_final_kernel(
    const int* __restrict__ cnt, const int* __restrict__ bsum,
    int* __restrict__ rs, int* __restrict__ cursor)
{
    __shared__ int s[256];
    const int tid = threadIdx.x;
    int i = blockIdx.x * 256 + tid;
    int v = (i < N) ? cnt[i] : 0;
    s[tid] = v;
    __syncthreads();
    #pragma unroll
    for (int off = 1; off < 256; off <<= 1) {
        int x = (tid >= off) ? s[tid - off] : 0;
        __syncthreads();
        s[tid] += x;
        __syncthreads();
    }
    int excl = s[tid] - v + bsum[blockIdx.x];
    if (i < N) { rs[i] = excl; cursor[i] = excl; }
}

__global__ __launch_bounds__(256) void fill_kernel(
    const int* __restrict__ src, const int* __restrict__ dst,
    int* __restrict__ cursor, int* __restrict__ csr_src, int* __restrict__ csr_eid)
{
    int e = blockIdx.x * 256 + threadIdx.x;
    if (e < E) {
        int d = dst[e];
        int pos = atomicAdd(&cursor[d], 1);
        csr_src[pos] = src[e];
        csr_eid[pos] = e;
    }
}

// ---------------------------------------------------------------------------
// hiddenAgg (once): haggB[d] = bf16( sum_{e: dst=d} relu(ea_e @ ee_w1 + ee_b1) )
// ---------------------------------------------------------------------------
__global__ __launch_bounds__(256) void hidden_agg_kernel(
    const float* __restrict__ ea, const float* __restrict__ ew1,
    const float* __restrict__ eb1,
    const int* __restrict__ rs, const int* __restrict__ csr_eid,
    short* __restrict__ haggB)
{
    const int tid = threadIdx.x;
    const int lane = tid & 63, wave = tid >> 6;
    const int n0 = blockIdx.x * 64;

    float4 w[ED];
    #pragma unroll
    for (int k = 0; k < ED; ++k)
        w[k] = *(const float4*)&ew1[k * H + 4 * lane];
    float4 bb = *(const float4*)&eb1[4 * lane];

    for (int t = 0; t < 16; ++t) {
        int n = n0 + wave * 16 + t;
        if (n >= N) continue;
        int s = rs[n], e = rs[n + 1];
        float4 acc = {0.f, 0.f, 0.f, 0.f};
        for (int j = s; j < e; ++j) {
            int eid = csr_eid[j];
            const float* ar = ea + (size_t)eid * ED;
            float4 hcol = bb;
            #pragma unroll
            for (int k = 0; k < ED; ++k) {
                float evk = ar[k];
                hcol.x += evk * w[k].x;
                hcol.y += evk * w[k].y;
                hcol.z += evk * w[k].z;
                hcol.w += evk * w[k].w;
            }
            acc.x += fmaxf(hcol.x, 0.f);
            acc.y += fmaxf(hcol.y, 0.f);
            acc.z += fmaxf(hcol.z, 0.f);
            acc.w += fmaxf(hcol.w, 0.f);
        }
        sv4 o = {f2bf(acc.x), f2bf(acc.y), f2bf(acc.z), f2bf(acc.w)};
        *(sv4*)&haggB[(size_t)n * H + 4 * lane] = o;
    }
}

// ---------------------------------------------------------------------------
// Weight prep
// ---------------------------------------------------------------------------
__global__ __launch_bounds__(256) void wx_part_kernel(
    const float* __restrict__ msgx_w, short* __restrict__ wxwe)
{
    int l = blockIdx.x >> 8, k = blockIdx.x & 255, n = threadIdx.x;
    wxwe[((size_t)(l * H + n)) * 512 + k] = f2bf(msgx_w[((size_t)l * H + k) * H + n]);
}

__global__ __launch_bounds__(256) void we_fuse_kernel(
    const float* __restrict__ ee_w2, const float* __restrict__ msge_w,
    short* __restrict__ wxwe)
{
    __shared__ float wrow[H];
    const int tid = threadIdx.x;
    const int l = blockIdx.x / H;
    const int t = blockIdx.x % H;
    wrow[tid] = ee_w2[t * H + tid];
    __syncthreads();
    const float* mw = msge_w + (size_t)l * H * H;
    float acc = 0.f;
    for (int k = 0; k < H; ++k)
        acc += wrow[k] * mw[k * H + tid];
    wxwe[((size_t)(l * H + tid)) * 512 + 256 + t] = f2bf(acc);
}

__global__ __launch_bounds__(256) void fuse_b_kernel(
    const float* __restrict__ ee_b2, const float* __restrict__ msge_w,
    float* __restrict__ be2)
{
    __shared__ float brow[H];
    const int tid = threadIdx.x;
    const int l = blockIdx.x;
    brow[tid] = ee_b2[tid];
    __syncthreads();
    const float* mw = msge_w + (size_t)l * H * H;
    float acc = 0.f;
    for (int k = 0; k < H; ++k)
        acc += brow[k] * mw[k * H + tid];
    be2[l * H + tid] = acc;
}

__global__ __launch_bounds__(256) void conv_bt_kernel(
    const float* __restrict__ w, short* __restrict__ bt)
{
    int mat = blockIdx.x >> 8, k = blockIdx.x & 255, n = threadIdx.x;
    bt[((size_t)mat * H + n) * H + k] = f2bf(w[((size_t)mat * H + k) * H + n]);
}

__global__ __launch_bounds__(256) void geow_bt_kernel(
    const float* __restrict__ w, short* __restrict__ bt)
{
    for (int i = threadIdx.x; i < 32 * 128; i += 256) {
        int n = i >> 7, k = i & 127;
        bt[i] = f2bf(w[k * 32 + n]);
    }
}

__global__ __launch_bounds__(256) void ninw1_bt_kernel(
    const float* __restrict__ w, short* __restrict__ bt)
{
    int i = blockIdx.x * 256 + threadIdx.x;
    int n = i >> 6, k = i & 63;
    bt[i] = f2bf(w[k * H + n]);
}

// ---------------------------------------------------------------------------
// Node input encoder (MFMA). M=64 nodes/block. Writes h_bf (bf16 only).
// ---------------------------------------------------------------------------
__global__ __launch_bounds__(256) void node_in_mfma_kernel(
    const float* __restrict__ x,
    const short* __restrict__ geo_wbt, const float* __restrict__ geo_b,
    const short* __restrict__ w1bt, const float* __restrict__ b1,
    const short* __restrict__ w2bt, const float* __restrict__ b2,
    short* __restrict__ h_bf)
{
    constexpr int KP = H + 8;
    constexpr int KX = 128 + 8;
    constexpr int KI = 64 + 8;
    __shared__ short A[64 * KP];
    __shared__ short XIN[64 * KI];
    const int tid = threadIdx.x;
    const int lane = tid & 63, wave = tid >> 6;
    const int quad = lane >> 4, lm = lane & 15;
    const int n0 = blockIdx.x * 64;
    const int nvalid = min(64, N - n0);
    const int ncol = wave * 64 + lm;

    for (int i = tid; i < 64 * 128; i += 256) {
        int row = i >> 7, k = i & 127;
        float v = (row < nvalid) ? x[(size_t)(n0 + row) * XD + k] : 0.f;
        A[row * KX + k] = f2bf(v);
    }
    for (int i = tid; i < 64 * 32; i += 256) {
        int row = i >> 5, k = i & 31;
        float v = (row < nvalid) ? x[(size_t)(n0 + row) * XD + 128 + k] : 0.f;
        XIN[row * KI + 32 + k] = f2bf(v);
    }
    __syncthreads();

    // geo GEMM
    {
        floatx4 c[2];
        float b0 = geo_b[lm], b1v = geo_b[16 + lm];
        c[0] = {b0, b0, b0, b0};
        c[1] = {b1v, b1v, b1v, b1v};
        #pragma unroll
        for (int ks = 0; ks < 4; ++ks) {
            short8 a  = *(const short8*)&A[(wave * 16 + lm) * KX + ks * 32 + quad * 8];
            short8 w0 = *(const short8*)&geo_wbt[(size_t)lm * 128 + ks * 32 + quad * 8];
            short8 w1 = *(const short8*)&geo_wbt[(size_t)(16 + lm) * 128 + ks * 32 + quad * 8];
            c[0] = __builtin_amdgcn_mfma_f32_16x16x32_bf16(a, w0, c[0], 0, 0, 0);
            c[1] = __builtin_amdgcn_mfma_f32_16x16x32_bf16(a, w1, c[1], 0, 0, 0);
        }
        #pragma unroll
        for (int nt = 0; nt < 2; ++nt)
            #pragma unroll
            for (int r = 0; r < 4; ++r) {
                int row = wave * 16 + quad * 4 + r;
                XIN[row * KI + nt * 16 + lm] = f2bf(fmaxf(c[nt][r], 0.f));
            }
    }
    __syncthreads();

    // GEMM1: K=64 -> hid (relu) into A
    floatx4 c1[4][4];
    #pragma unroll
    for (int nt = 0; nt < 4; ++nt) {
        float bb = b1[ncol + nt * 16];
        #pragma unroll
        for (int mt = 0; mt < 4; ++mt) {
            c1[mt][nt][0] = bb; c1[mt][nt][1] = bb;
            c1[mt][nt][2] = bb; c1[mt][nt][3] = bb;
        }
    }
    #pragma unroll
    for (int ks = 0; ks < 2; ++ks) {
        short8 a[4], b[4];
        #pragma unroll
        for (int mt = 0; mt < 4; ++mt)
            a[mt] = *(const short8*)&XIN[(mt * 16 + lm) * KI + ks * 32 + quad * 8];
        #pragma unroll
        for (int nt = 0; nt < 4; ++nt)
            b[nt] = *(const short8*)&w1bt[(size_t)(ncol + nt * 16) * 64 + ks * 32 + quad * 8];
        #pragma unroll
        for (int mt = 0; mt < 4; ++mt)
            #pragma unroll
            for (int nt = 0; nt < 4; ++nt)
                c1[mt][nt] = __builtin_amdgcn_mfma_f32_16x16x32_bf16(a[mt], b[nt], c1[mt][nt], 0, 0, 0);
    }
    __syncthreads();
    #pragma unroll
    for (int mt = 0; mt < 4; ++mt)
        #pragma unroll
        for (int nt = 0; nt < 4; ++nt) {
            int col = ncol + nt * 16;
            #pragma unroll
            for (int r = 0; r < 4; ++r) {
                int row = mt * 16 + quad * 4 + r;
                A[row * KP + col] = f2bf(fmaxf(c1[mt][nt][r], 0.f));
            }
        }
    __syncthreads();

    // GEMM2: K=256 -> h_bf
    floatx4 c2[4][4];
    #pragma unroll
    for (int nt = 0; nt < 4; ++nt) {
        float bb = b2[ncol + nt * 16];
        #pragma unroll
        for (int mt = 0; mt < 4; ++mt) {
            c2[mt][nt][0] = bb; c2[mt][nt][1] = bb;
            c2[mt][nt][2] = bb; c2[mt][nt][3] = bb;
        }
    }
    #pragma unroll
    for (int ks = 0; ks < 8; ++ks) {
        short8 a[4], b[4];
        #pragma unroll
        for (int mt = 0; mt < 4; ++mt)
            a[mt] = *(const short8*)&A[(mt * 16 + lm) * KP + ks * 32 + quad * 8];
        #pragma unroll
        for (int nt = 0; nt < 4; ++nt)
            b[nt] = *(const short8*)&w2bt[(size_t)(ncol + nt * 16) * H + ks * 32 + quad * 8];
        #pragma unroll
        for (int mt = 0; mt < 4; ++mt)
            #pragma unroll
            for (int nt = 0; nt < 4; ++nt)
                c2[mt][nt] = __builtin_amdgcn_mfma_f32_16x16x32_bf16(a[mt], b[nt], c2[mt][nt], 0, 0, 0);
    }
    #pragma unroll
    for (int mt = 0; mt < 4; ++mt)
        #pragma unroll
        for (int r = 0; r < 4; ++r) {
            int row = mt * 16 + quad * 4 + r;
            if (row < nvalid) {
                #pragma unroll
                for (int nt = 0; nt < 4; ++nt)
                    h_bf[(size_t)(n0 + row) * H + ncol + nt * 16] = f2bf(c2[mt][nt][r]);
            }
        }
}

// ---------------------------------------------------------------------------
// Fused layer kernel: gather(h_in_bf) -> K=512 GEMM -> MLP -> LN
// h_out_bf (layers 0..2) and/or h_out_f32 (last layer) may be null.
// ---------------------------------------------------------------------------
__global__ __launch_bounds__(256) void layer_kernel(
    const short* __restrict__ h_in_bf, short* __restrict__ h_out_bf,
    float* __restrict__ h_out_f32,
    const int* __restrict__ rs, const int* __restrict__ csr_src,
    const short* __restrict__ haggB,
    const short* __restrict__ wxwe, const float* __restrict__ be2,
    const short* __restrict__ u1bt, const float* __restrict__ b1,
    const short* __restrict__ u2bt, const float* __restrict__ b2,
    const float* __restrict__ lng, const float* __restrict__ lnb)
{
    constexpr int KP2 = 512 + 8;
    constexpr int KP  = H + 8;
    __shared__ short A[64 * KP2];
    __shared__ int rsL[65];
    __shared__ float psum[64][4], psq[64][4];
    __shared__ float muS[64], rsS[64];
    const int tid  = threadIdx.x;
    const int lane = tid & 63, wave = tid >> 6;
    const int quad = lane >> 4, lm = lane & 15;
    const int n0 = blockIdx.x * 64;
    const int nvalid = min(64, N - n0);
    const int ncol = wave * 64 + lm;

    if (tid < 65) rsL[tid] = rs[min(n0 + tid, N)];
    __syncthreads();

    // --- stage 1: gather bf16 rows, f32 accumulate ---
    for (int t = 0; t < 16; ++t) {
        int row = wave * 16 + t;
        int s = rsL[row], e = rsL[row + 1];
        float4 acc = {0.f, 0.f, 0.f, 0.f};
        int j = s;
        for (; j + 1 < e; j += 2) {
            int s0 = csr_src[j], s1 = csr_src[j + 1];
            sv4 v0 = *(const sv4*)&h_in_bf[(size_t)s0 * H + 4 * lane];
            sv4 v1 = *(const sv4*)&h_in_bf[(size_t)s1 * H + 4 * lane];
            acc.x += bf2f(v0.x) + bf2f(v1.x);
            acc.y += bf2f(v0.y) + bf2f(v1.y);
            acc.z += bf2f(v0.z) + bf2f(v1.z);
            acc.w += bf2f(v0.w) + bf2f(v1.w);
        }
        if (j < e) {
            int s0 = csr_src[j];
            sv4 v0 = *(const sv4*)&h_in_bf[(size_t)s0 * H + 4 * lane];
            acc.x += bf2f(v0.x); acc.y += bf2f(v0.y);
            acc.z += bf2f(v0.z); acc.w += bf2f(v0.w);
        }
        sv4 o = {f2bf(acc.x), f2bf(acc.y), f2bf(acc.z), f2bf(acc.w)};
        *(sv4*)&A[row * KP2 + 4 * lane] = o;
    }
    // --- stage 1b: hiddenAgg -> A cols 256..511 ---
    for (int i = tid; i < 64 * 64; i += 256) {
        int row = i >> 6, q = i & 63;
        sv4 v = {0, 0, 0, 0};
        if (row < nvalid)
            v = *(const sv4*)&haggB[(size_t)(n0 + row) * H + 4 * q];
        *(sv4*)&A[row * KP2 + 256 + 4 * q] = v;
    }
    __syncthreads();

    // --- stage 2: K=512 GEMM, acc init deg*be2 ---
    floatx4 c1[4][4];
    #pragma unroll
    for (int nt = 0; nt < 4; ++nt) {
        float bb = be2[ncol + nt * 16];
        #pragma unroll
        for (int mt = 0; mt < 4; ++mt) {
            #pragma unroll
            for (int r = 0; r < 4; ++r) {
                int row = mt * 16 + quad * 4 + r;
                float deg = (float)(rsL[row + 1] - rsL[row]);
                c1[mt][nt][r] = deg * bb;
            }
        }
    }
    #pragma unroll
    for (int ks = 0; ks < 16; ++ks) {
        short8 a[4], b[4];
        #pragma unroll
        for (int mt = 0; mt < 4; ++mt)
            a[mt] = *(const short8*)&A[(mt * 16 + lm) * KP2 + ks * 32 + quad * 8];
        #pragma unroll
        for (int nt = 0; nt < 4; ++nt)
            b[nt] = *(const short8*)&wxwe[(size_t)(ncol + nt * 16) * 512 + ks * 32 + quad * 8];
        #pragma unroll
        for (int mt = 0; mt < 4; ++mt)
            #pragma unroll
            for (int nt = 0; nt < 4; ++nt)
                c1[mt][nt] = __builtin_amdgcn_mfma_f32_16x16x32_bf16(a[mt], b[nt], c1[mt][nt], 0, 0, 0);
    }
    __syncthreads();
    #pragma unroll
    for (int mt = 0; mt < 4; ++mt)
        #pragma unroll
        for (int nt = 0; nt < 4; ++nt) {
            int col = ncol + nt * 16;
            #pragma unroll
            for (int r = 0; r < 4; ++r) {
                int row = mt * 16 + quad * 4 + r;
                A[row * KP + col] = f2bf(c1[mt][nt][r]);
            }
        }
    __syncthreads();

    // --- stage 3: GEMM K=256 @W1 + b1, relu -> A ---
    floatx4 c2[4][4];
    #pragma unroll
    for (int nt = 0; nt < 4; ++nt) {
        float bb = b1[ncol + nt * 16];
        #pragma unroll
        for (int mt = 0; mt < 4; ++mt) {
            c2[mt][nt][0] = bb; c2[mt][nt][1] = bb;
            c2[mt][nt][2] = bb; c2[mt][nt][3] = bb;
        }
    }
    #pragma unroll
    for (int ks = 0; ks < 8; ++ks) {
        short8 a[4], b[4];
        #pragma unroll
        for (int mt = 0; mt < 4; ++mt)
            a[mt] = *(const short8*)&A[(mt * 16 + lm) * KP + ks * 32 + quad * 8];
        #pragma unroll
        for (int nt = 0; nt < 4; ++nt)
            b[nt] = *(const short8*)&u1bt[(size_t)(ncol + nt * 16) * H + ks * 32 + quad * 8];
        #pragma unroll
        for (int mt = 0; mt < 4; ++mt)
            #pragma unroll
            for (int nt = 0; nt < 4; ++nt)
                c2[mt][nt] = __builtin_amdgcn_mfma_f32_16x16x32_bf16(a[mt], b[nt], c2[mt][nt], 0, 0, 0);
    }
    __syncthreads();
    #pragma unroll
    for (int mt = 0; mt < 4; ++mt)
        #pragma unroll
        for (int nt = 0; nt < 4; ++nt) {
            int col = ncol + nt * 16;
            #pragma unroll
            for (int r = 0; r < 4; ++r) {
                int row = mt * 16 + quad * 4 + r;
                A[row * KP + col] = f2bf(fmaxf(c2[mt][nt][r], 0.f));
            }
        }
    __syncthreads();

    // --- stage 4: GEMM K=256 @W2 + b2 + residual; LN; store ---
    floatx4 c3[4][4];
    #pragma unroll
    for (int nt = 0; nt < 4; ++nt) {
        float bb = b2[ncol + nt * 16];
        #pragma unroll
        for (int mt = 0; mt < 4; ++mt) {
            c3[mt][nt][0] = bb; c3[mt][nt][1] = bb;
            c3[mt][nt][2] = bb; c3[mt][nt][3] = bb;
        }
    }
    #pragma unroll
    for (int ks = 0; ks < 8; ++ks) {
        short8 a[4], b[4];
        #pragma unroll
        for (int mt = 0; mt < 4; ++mt)
            a[mt] = *(const short8*)&A[(mt * 16 + lm) * KP + ks * 32 + quad * 8];
        #pragma unroll
        for (int nt = 0; nt < 4; ++nt)
            b[nt] = *(const short8*)&u2bt[(size_t)(ncol + nt * 16) * H + ks * 32 + quad * 8];
        #pragma unroll
        for (int mt = 0; mt < 4; ++mt)
            #pragma unroll
            for (int nt = 0; nt < 4; ++nt)
                c3[mt][nt] = __builtin_amdgcn_mfma_f32_16x16x32_bf16(a[mt], b[nt], c3[mt][nt], 0, 0, 0);
    }
    #pragma unroll
    for (int mt = 0; mt < 4; ++mt)
        #pragma unroll
        for (int r = 0; r < 4; ++r) {
            int row = mt * 16 + quad * 4 + r;
            if (row < nvalid) {
                #pragma unroll
                for (int nt = 0; nt < 4; ++nt)
                    c3[mt][nt][r] += bf2f(h_in_bf[(size_t)(n0 + row) * H + ncol + nt * 16]);
            }
        }

    // LN partials
    #pragma unroll
    for (int mt = 0; mt < 4; ++mt)
        #pragma unroll
        for (int r = 0; r < 4; ++r) {
            float s = 0.f, q = 0.f;
            #pragma unroll
            for (int nt = 0; nt < 4; ++nt) {
                float v = c3[mt][nt][r];
                s += v; q += v * v;
            }
            #pragma unroll
            for (int m = 1; m < 16; m <<= 1) {
                s += __shfl_xor(s, m, 64);
                q += __shfl_xor(q, m, 64);
            }
            if (lm == 0) {
                int row = mt * 16 + quad * 4 + r;
                psum[row][wave] = s;
                psq[row][wave]  = q;
            }
        }
    __syncthreads();
    if (tid < 64) {
        float s = psum[tid][0] + psum[tid][1] + psum[tid][2] + psum[tid][3];
        float q = psq[tid][0] + psq[tid][1] + psq[tid][2] + psq[tid][3];
        float mu = s * (1.f / H);
        float var = q * (1.f / H) - mu * mu;
        muS[tid] = mu;
        rsS[tid] = rsqrtf(fmaxf(var, 0.f) + 1e-5f);
    }
    __syncthreads();

    float g[4], bb4[4];
    #pragma unroll
    for (int nt = 0; nt < 4; ++nt) {
        g[nt]   = lng[ncol + nt * 16];
        bb4[nt] = lnb[ncol + nt * 16];
    }
    const bool wbf = (h_out_bf != nullptr);
    const bool wf  = (h_out_f32 != nullptr);
    #pragma unroll
    for (int mt = 0; mt < 4; ++mt)
        #pragma unroll
        for (int r = 0; r < 4; ++r) {
            int row = mt * 16 + quad * 4 + r;
            if (row < nvalid) {
                float mu = muS[row], rsv = rsS[row];
                #pragma unroll
                for (int nt = 0; nt < 4; ++nt) {
                    float o = (c3[mt][nt][r] - mu) * rsv * g[nt] + bb4[nt];
                    size_t off = (size_t)(n0 + row) * H + ncol + nt * 16;
                    if (wbf) h_out_bf[off] = f2bf(o);
                    if (wf)  h_out_f32[off] = o;
                }
            }
        }
}

// ---------------------------------------------------------------------------
// Pooling (batch sorted -> LDS accumulate, flush on change)
// ---------------------------------------------------------------------------
__global__ __launch_bounds__(256) void pool_kernel(
    const float* __restrict__ h, const int* __restrict__ batch,
    const int* __restrict__ ntype,
    float* __restrict__ zsum, float* __restrict__ zcnt)
{
    constexpr int CHUNK = 256;
    __shared__ float acc[3][H];
    __shared__ float cnt[3];
    const int tid = threadIdx.x;
    const int n0 = blockIdx.x * CHUNK;
    const int nend = min(n0 + CHUNK, N);

    for (int q = 0; q < 3; ++q) acc[q][tid] = 0.f;
    if (tid == 0) { cnt[0] = 0.f; cnt[1] = 0.f; cnt[2] = 0.f; }
    __syncthreads();

    int cur = batch[n0];
    for (int n = n0; n < nend; ++n) {
        int b = batch[n];
        int t = ntype[n];
        if (b != cur) {
            for (int q = 0; q < 3; ++q) {
                atomicAdd(&zsum[cur * (3 * H) + q * H + tid], acc[q][tid]);
                acc[q][tid] = 0.f;
            }
            if (tid == 0)
                for (int q = 0; q < 3; ++q) { atomicAdd(&zcnt[cur * 3 + q], cnt[q]); cnt[q] = 0.f; }
            cur = b;
        }
        acc[t][tid] += h[(size_t)n * H + tid];
        if (tid == 0) cnt[t] += 1.f;
    }
    for (int q = 0; q < 3; ++q)
        atomicAdd(&zsum[cur * (3 * H) + q * H + tid], acc[q][tid]);
    if (tid == 0)
        for (int q = 0; q < 3; ++q) atomicAdd(&zcnt[cur * 3 + q], cnt[q]);
}

__global__ __launch_bounds__(256) void finalize_kernel(
    const float* __restrict__ zsum, const float* __restrict__ zcnt,
    float* __restrict__ out)
{
    int idx = blockIdx.x * 256 + threadIdx.x;
    if (idx >= B * 3 * H) return;
    int b = idx / (3 * H);
    int c = idx % (3 * H);
    int t = c / H;
    float cn = zcnt[b * 3 + t];
    out[idx] = zsum[idx] / fmaxf(cn, 1.f);
}

__global__ __launch_bounds__(256) void batch_out_kernel(
    const int* __restrict__ batch, float* __restrict__ out)
{
    int idx = blockIdx.x * 256 + threadIdx.x;
    if (idx < N) out[idx] = (float)batch[idx];
}

// ---------------------------------------------------------------------------
extern "C" void kernel_launch(void* const* d_in, const int* in_sizes, int n_in,
                              void* d_out, int out_size, void* d_ws, size_t ws_size,
                              hipStream_t stream) {
    const float* x         = (const float*)d_in[0];
    const float* edge_attr = (const float*)d_in[1];
    const float* geo_w     = (const float*)d_in[2];
    const float* geo_b     = (const float*)d_in[3];
    const float* nin_w1    = (const float*)d_in[4];
    const float* nin_b1    = (const float*)d_in[5];
    const float* nin_w2    = (const float*)d_in[6];
    const float* nin_b2    = (const float*)d_in[7];
    const float* ee_w1     = (const float*)d_in[8];
    const float* ee_b1     = (const float*)d_in[9];
    const float* ee_w2     = (const float*)d_in[10];
    const float* ee_b2     = (const float*)d_in[11];
    const float* msgx_w    = (const float*)d_in[12];
    const float* msge_w    = (const float*)d_in[13];
    const float* upd_w1    = (const float*)d_in[14];
    const float* upd_b1    = (const float*)d_in[15];
    const float* upd_w2    = (const float*)d_in[16];
    const float* upd_b2    = (const float*)d_in[17];
    const float* ln_g      = (const float*)d_in[18];
    const float* ln_b      = (const float*)d_in[19];
    const int*   edge_index= (const int*)d_in[20];
    const int*   batch     = (const int*)d_in[21];
    const int*   node_type = (const int*)d_in[22];

    float* out = (float*)d_out;
    float* hf  = out + B * 3 * H;                  // final f32 h -> d_out

    // Workspace layout (~82 MB):
    short* h0_bf   = (short*)d_ws;                     // [N,H] bf16  25.6 MB
    short* h1_bf   = h0_bf + (size_t)N * H;            // [N,H] bf16  25.6 MB
    short* haggB   = h1_bf + (size_t)N * H;            // [N,H] bf16  25.6 MB
    short* wxwe    = haggB + (size_t)N * H;            // [L,H,512] bf16
    short* u1bt    = wxwe + (size_t)L * H * 512;       // [L,H,H] bf16
    short* u2bt    = u1bt + (size_t)L * H * H;         // [L,H,H] bf16
    short* geowbt  = u2bt + (size_t)L * H * H;         // [32,128]
    short* w1bt    = geowbt + 32 * 128;                // [H,64]
    short* w2bt    = w1bt + H * 64;                    // [H,H]
    float* be2     = (float*)(w2bt + H * H);           // [L,H]
    float* zsum    = be2 + L * H;                      // [B,3H]
    float* zcnt    = zsum + B * 3 * H;                 // [B,3]
    int*   rowcnt  = (int*)(zcnt + B * 3);             // [N]
    int*   rs      = rowcnt + N;                       // [N+1]
    int*   cursor  = rs + N + 1;                       // [N]
    int*   bsum    = cursor + N;                       // [256]
    int*   csr_src = bsum + 256;                       // [E]
    int*   csr_eid = csr_src + E;                      // [E]

    const int* src = edge_index;
    const int* dst = edge_index + E;

    const int nscan = (N + 255) / 256;   // 196 blocks <= 256

    // --- CSR build ---
    hipMemsetAsync(rowcnt, 0, (size_t)N * sizeof(int), stream);
    hist_kernel<<<(E + 255) / 256, 256, 0, stream>>>(dst, rowcnt);
    scan_partial_kernel<<<nscan, 256, 0, stream>>>(rowcnt, bsum);
    scan_bsum_kernel<<<1, 256, 0, stream>>>(bsum, nscan, rs + N);
    scan_final_kernel<<<nscan, 256, 0, stream>>>(rowcnt, bsum, rs, cursor);
    fill_kernel<<<(E + 255) / 256, 256, 0, stream>>>(src, dst, cursor, csr_src, csr_eid);

    // --- weight prep ---
    wx_part_kernel<<<L * 256, 256, 0, stream>>>(msgx_w, wxwe);
    we_fuse_kernel<<<L * H, 256, 0, stream>>>(ee_w2, msge_w, wxwe);
    fuse_b_kernel<<<L, 256, 0, stream>>>(ee_b2, msge_w, be2);
    conv_bt_kernel<<<L * 256, 256, 0, stream>>>(upd_w1, u1bt);
    conv_bt_kernel<<<L * 256, 256, 0, stream>>>(upd_w2, u2bt);
    conv_bt_kernel<<<256, 256, 0, stream>>>(nin_w2, w2bt);
    geow_bt_kernel<<<1, 256, 0, stream>>>(geo_w, geowbt);
    ninw1_bt_kernel<<<64, 256, 0, stream>>>(nin_w1, w1bt);

    // --- hiddenAgg (layer-independent) ---
    hidden_agg_kernel<<<(N + 63) / 64, 256, 0, stream>>>(
        edge_attr, ee_w1, ee_b1, rs, csr_eid, haggB);

    // --- node encoder -> h0_bf ---
    node_in_mfma_kernel<<<(N + 63) / 64, 256, 0, stream>>>(
        x, geowbt, geo_b, w1bt, nin_b1, w2bt, nin_b2, h0_bf);

    // --- layers: bf16 ping-pong; last layer writes f32 to d_out ---
    const int lgrid = (N + 63) / 64;
    for (int l = 0; l < L; ++l) {
        const short* hin  = (l & 1) ? h1_bf : h0_bf;
        short* hout_bf    = (l == L - 1) ? nullptr : ((l & 1) ? h0_bf : h1_bf);
        float* hout_f32   = (l == L - 1) ? hf : nullptr;
        layer_kernel<<<lgrid, 256, 0, stream>>>(
            hin, hout_bf, hout_f32, rs, csr_src, haggB,
            wxwe + (size_t)l * H * 512, be2 + (size_t)l * H,
            u1bt + (size_t)l * H * H, upd_b1 + (size_t)l * H,
            u2bt + (size_t)l * H * H, upd_b2 + (size_t)l * H,
            ln_g + (size_t)l * H, ln_b + (size_t)l * H);
    }

    // --- pooling ---
    hipMemsetAsync(zsum, 0, (size_t)(B * 3 * H + B * 3) * sizeof(float), stream);
    pool_kernel<<<(N + 255) / 256, 256, 0, stream>>>(hf, batch, node_type, zsum, zcnt);
    finalize_kernel<<<(B * 3 * H + 255) / 256, 256, 0, stream>>>(zsum, zcnt, out);
    batch_out_kernel<<<(N + 255) / 256, 256, 0, stream>>>(batch, out + B * 3 * H + (size_t)N * H);
}

// Round 7
// 1201.583 us; speedup vs baseline: 7.1595x; 1.0594x over previous
//
#include <hip/hip_runtime.h>

// Problem constants (from reference)
constexpr int N  = 50000;
constexpr int E  = 300000;
constexpr int B  = 8;
constexpr int XD = 160;
constexpr int ED = 16;
constexpr int H  = 256;
constexpr int L  = 4;
constexpr int G  = 32;

typedef __attribute__((ext_vector_type(8))) short short8;
typedef __attribute__((ext_vector_type(4))) short sv4;
typedef __attribute__((ext_vector_type(4))) float floatx4;

// f32 -> bf16 round-to-nearest-even
__device__ __forceinline__ short f2bf(float f) {
    union { float f; unsigned u; } v; v.f = f;
    unsigned r = (v.u + 0x7fffu + ((v.u >> 16) & 1u)) >> 16;
    return (short)r;
}
__device__ __forceinline__ float bf2f(short s) {
    union { unsigned u; float f; } v;
    v.u = ((unsigned)(unsigned short)s) << 16;
    return v.f;
}

// ---------------------------------------------------------------------------
// CSR build: histogram, 3-pass multi-block scan, fill
// ---------------------------------------------------------------------------
__global__ __launch_bounds__(256) void hist_kernel(
    const int* __restrict__ dst, int* __restrict__ cnt)
{
    int e = blockIdx.x * 256 + threadIdx.x;
    if (e < E) atomicAdd(&cnt[dst[e]], 1);
}

__global__ __launch_bounds__(256) void scan_partial_kernel(
    const int* __restrict__ cnt, int* __restrict__ bsum)
{
    __shared__ int s[256];
    const int tid = threadIdx.x;
    int i = blockIdx.x * 256 + tid;
    s[tid] = (i < N) ? cnt[i] : 0;
    __syncthreads();
    #pragma unroll
    for (int off = 128; off > 0; off >>= 1) {
        if (tid < off) s[tid] += s[tid + off];
        __syncthreads();
    }
    if (tid == 0) bsum[blockIdx.x] = s[0];
}

__global__ __launch_bounds__(256) void scan_bsum_kernel(
    int* __restrict__ bsum, int nb, int* __restrict__ rsN)
{
    __shared__ int s[256];
    const int tid = threadIdx.x;
    int v = (tid < nb) ? bsum[tid] : 0;
    s[tid] = v;
    __syncthreads();
    #pragma unroll
    for (int off = 1; off < 256; off <<= 1) {
        int x = (tid >= off) ? s[tid - off] : 0;
        __syncthreads();
        s[tid] += x;
        __syncthreads();
    }
    if (tid < nb) bsum[tid] = s[tid] - v;
    if (tid == 255) *rsN = s[255];
}

__global__ __launch_bounds__(256) void scan_final_kernel(
    const int* __restrict__ cnt, const int* __restrict__ bsum,
    int* __restrict__ rs, int* __restrict__ cursor)
{
    __shared__ int s[256];
    const int tid = threadIdx.x;
    int i = blockIdx.x * 256 + tid;
    int v = (i < N) ? cnt[i] : 0;
    s[tid] = v;
    __syncthreads();
    #pragma unroll
    for (int off = 1; off < 256; off <<= 1) {
        int x = (tid >= off) ? s[tid - off] : 0;
        __syncthreads();
        s[tid] += x;
        __syncthreads();
    }
    int excl = s[tid] - v + bsum[blockIdx.x];
    if (i < N) { rs[i] = excl; cursor[i] = excl; }
}

__global__ __launch_bounds__(256) void fill_kernel(
    const int* __restrict__ src, const int* __restrict__ dst,
    int* __restrict__ cursor, int* __restrict__ csr_src, int* __restrict__ csr_eid)
{
    int e = blockIdx.x * 256 + threadIdx.x;
    if (e < E) {
        int d = dst[e];
        int pos = atomicAdd(&cursor[d], 1);
        csr_src[pos] = src[e];
        csr_eid[pos] = e;
    }
}

// ---------------------------------------------------------------------------
// hiddenAgg: haggB[d] = bf16( sum_{e: dst=d} relu(ea_e @ ee_w1 + ee_b1) )
// 4 nodes per wave (grid x4 vs before), degree loop unrolled x2 for ILP.
// ---------------------------------------------------------------------------
__global__ __launch_bounds__(256) void hidden_agg_kernel(
    const float* __restrict__ ea, const float* __restrict__ ew1,
    const float* __restrict__ eb1,
    const int* __restrict__ rs, const int* __restrict__ csr_eid,
    short* __restrict__ haggB)
{
    const int tid = threadIdx.x;
    const int lane = tid & 63, wave = tid >> 6;
    const int n0 = blockIdx.x * 16;          // 16 nodes/block, 4/wave

    float4 w[ED];
    #pragma unroll
    for (int k = 0; k < ED; ++k)
        w[k] = *(const float4*)&ew1[k * H + 4 * lane];
    float4 bb = *(const float4*)&eb1[4 * lane];

    #pragma unroll
    for (int t = 0; t < 4; ++t) {
        int n = n0 + wave * 4 + t;
        if (n >= N) continue;
        int s = rs[n], e = rs[n + 1];
        float4 acc = {0.f, 0.f, 0.f, 0.f};
        int j = s;
        for (; j + 1 < e; j += 2) {
            int e0 = csr_eid[j], e1 = csr_eid[j + 1];
            const float* a0 = ea + (size_t)e0 * ED;
            const float* a1 = ea + (size_t)e1 * ED;
            float4 h0 = bb, h1 = bb;
            #pragma unroll
            for (int k = 0; k < ED; ++k) {
                float v0 = a0[k], v1 = a1[k];
                h0.x += v0 * w[k].x; h1.x += v1 * w[k].x;
                h0.y += v0 * w[k].y; h1.y += v1 * w[k].y;
                h0.z += v0 * w[k].z; h1.z += v1 * w[k].z;
                h0.w += v0 * w[k].w; h1.w += v1 * w[k].w;
            }
            acc.x += fmaxf(h0.x, 0.f) + fmaxf(h1.x, 0.f);
            acc.y += fmaxf(h0.y, 0.f) + fmaxf(h1.y, 0.f);
            acc.z += fmaxf(h0.z, 0.f) + fmaxf(h1.z, 0.f);
            acc.w += fmaxf(h0.w, 0.f) + fmaxf(h1.w, 0.f);
        }
        if (j < e) {
            int e0 = csr_eid[j];
            const float* a0 = ea + (size_t)e0 * ED;
            float4 h0 = bb;
            #pragma unroll
            for (int k = 0; k < ED; ++k) {
                float v0 = a0[k];
                h0.x += v0 * w[k].x; h0.y += v0 * w[k].y;
                h0.z += v0 * w[k].z; h0.w += v0 * w[k].w;
            }
            acc.x += fmaxf(h0.x, 0.f); acc.y += fmaxf(h0.y, 0.f);
            acc.z += fmaxf(h0.z, 0.f); acc.w += fmaxf(h0.w, 0.f);
        }
        sv4 o = {f2bf(acc.x), f2bf(acc.y), f2bf(acc.z), f2bf(acc.w)};
        *(sv4*)&haggB[(size_t)n * H + 4 * lane] = o;
    }
}

// ---------------------------------------------------------------------------
// Weight prep
// ---------------------------------------------------------------------------
__global__ __launch_bounds__(256) void wx_part_kernel(
    const float* __restrict__ msgx_w, short* __restrict__ wxwe)
{
    int l = blockIdx.x >> 8, k = blockIdx.x & 255, n = threadIdx.x;
    wxwe[((size_t)(l * H + n)) * 512 + k] = f2bf(msgx_w[((size_t)l * H + k) * H + n]);
}

__global__ __launch_bounds__(256) void we_fuse_kernel(
    const float* __restrict__ ee_w2, const float* __restrict__ msge_w,
    short* __restrict__ wxwe)
{
    __shared__ float wrow[H];
    const int tid = threadIdx.x;
    const int l = blockIdx.x / H;
    const int t = blockIdx.x % H;
    wrow[tid] = ee_w2[t * H + tid];
    __syncthreads();
    const float* mw = msge_w + (size_t)l * H * H;
    float acc = 0.f;
    for (int k = 0; k < H; ++k)
        acc += wrow[k] * mw[k * H + tid];
    wxwe[((size_t)(l * H + tid)) * 512 + 256 + t] = f2bf(acc);
}

__global__ __launch_bounds__(256) void fuse_b_kernel(
    const float* __restrict__ ee_b2, const float* __restrict__ msge_w,
    float* __restrict__ be2)
{
    __shared__ float brow[H];
    const int tid = threadIdx.x;
    const int l = blockIdx.x;
    brow[tid] = ee_b2[tid];
    __syncthreads();
    const float* mw = msge_w + (size_t)l * H * H;
    float acc = 0.f;
    for (int k = 0; k < H; ++k)
        acc += brow[k] * mw[k * H + tid];
    be2[l * H + tid] = acc;
}

__global__ __launch_bounds__(256) void conv_bt_kernel(
    const float* __restrict__ w, short* __restrict__ bt)
{
    int mat = blockIdx.x >> 8, k = blockIdx.x & 255, n = threadIdx.x;
    bt[((size_t)mat * H + n) * H + k] = f2bf(w[((size_t)mat * H + k) * H + n]);
}

__global__ __launch_bounds__(256) void geow_bt_kernel(
    const float* __restrict__ w, short* __restrict__ bt)
{
    for (int i = threadIdx.x; i < 32 * 128; i += 256) {
        int n = i >> 7, k = i & 127;
        bt[i] = f2bf(w[k * 32 + n]);
    }
}

__global__ __launch_bounds__(256) void ninw1_bt_kernel(
    const float* __restrict__ w, short* __restrict__ bt)
{
    int i = blockIdx.x * 256 + threadIdx.x;
    int n = i >> 6, k = i & 63;
    bt[i] = f2bf(w[k * H + n]);
}

// ---------------------------------------------------------------------------
// Node input encoder (MFMA). M=64 nodes/block. Writes h_bf (bf16 only).
// ---------------------------------------------------------------------------
__global__ __launch_bounds__(256) void node_in_mfma_kernel(
    const float* __restrict__ x,
    const short* __restrict__ geo_wbt, const float* __restrict__ geo_b,
    const short* __restrict__ w1bt, const float* __restrict__ b1,
    const short* __restrict__ w2bt, const float* __restrict__ b2,
    short* __restrict__ h_bf)
{
    constexpr int KP = H + 8;
    constexpr int KX = 128 + 8;
    constexpr int KI = 64 + 8;
    __shared__ short A[64 * KP];
    __shared__ short XIN[64 * KI];
    const int tid = threadIdx.x;
    const int lane = tid & 63, wave = tid >> 6;
    const int quad = lane >> 4, lm = lane & 15;
    const int n0 = blockIdx.x * 64;
    const int nvalid = min(64, N - n0);
    const int ncol = wave * 64 + lm;

    for (int i = tid; i < 64 * 128; i += 256) {
        int row = i >> 7, k = i & 127;
        float v = (row < nvalid) ? x[(size_t)(n0 + row) * XD + k] : 0.f;
        A[row * KX + k] = f2bf(v);
    }
    for (int i = tid; i < 64 * 32; i += 256) {
        int row = i >> 5, k = i & 31;
        float v = (row < nvalid) ? x[(size_t)(n0 + row) * XD + 128 + k] : 0.f;
        XIN[row * KI + 32 + k] = f2bf(v);
    }
    __syncthreads();

    // geo GEMM
    {
        floatx4 c[2];
        float b0 = geo_b[lm], b1v = geo_b[16 + lm];
        c[0] = {b0, b0, b0, b0};
        c[1] = {b1v, b1v, b1v, b1v};
        #pragma unroll
        for (int ks = 0; ks < 4; ++ks) {
            short8 a  = *(const short8*)&A[(wave * 16 + lm) * KX + ks * 32 + quad * 8];
            short8 w0 = *(const short8*)&geo_wbt[(size_t)lm * 128 + ks * 32 + quad * 8];
            short8 w1 = *(const short8*)&geo_wbt[(size_t)(16 + lm) * 128 + ks * 32 + quad * 8];
            c[0] = __builtin_amdgcn_mfma_f32_16x16x32_bf16(a, w0, c[0], 0, 0, 0);
            c[1] = __builtin_amdgcn_mfma_f32_16x16x32_bf16(a, w1, c[1], 0, 0, 0);
        }
        #pragma unroll
        for (int nt = 0; nt < 2; ++nt)
            #pragma unroll
            for (int r = 0; r < 4; ++r) {
                int row = wave * 16 + quad * 4 + r;
                XIN[row * KI + nt * 16 + lm] = f2bf(fmaxf(c[nt][r], 0.f));
            }
    }
    __syncthreads();

    // GEMM1: K=64 -> hid (relu) into A
    floatx4 c1[4][4];
    #pragma unroll
    for (int nt = 0; nt < 4; ++nt) {
        float bb = b1[ncol + nt * 16];
        #pragma unroll
        for (int mt = 0; mt < 4; ++mt) {
            c1[mt][nt][0] = bb; c1[mt][nt][1] = bb;
            c1[mt][nt][2] = bb; c1[mt][nt][3] = bb;
        }
    }
    #pragma unroll
    for (int ks = 0; ks < 2; ++ks) {
        short8 a[4], b[4];
        #pragma unroll
        for (int mt = 0; mt < 4; ++mt)
            a[mt] = *(const short8*)&XIN[(mt * 16 + lm) * KI + ks * 32 + quad * 8];
        #pragma unroll
        for (int nt = 0; nt < 4; ++nt)
            b[nt] = *(const short8*)&w1bt[(size_t)(ncol + nt * 16) * 64 + ks * 32 + quad * 8];
        #pragma unroll
        for (int mt = 0; mt < 4; ++mt)
            #pragma unroll
            for (int nt = 0; nt < 4; ++nt)
                c1[mt][nt] = __builtin_amdgcn_mfma_f32_16x16x32_bf16(a[mt], b[nt], c1[mt][nt], 0, 0, 0);
    }
    __syncthreads();
    #pragma unroll
    for (int mt = 0; mt < 4; ++mt)
        #pragma unroll
        for (int nt = 0; nt < 4; ++nt) {
            int col = ncol + nt * 16;
            #pragma unroll
            for (int r = 0; r < 4; ++r) {
                int row = mt * 16 + quad * 4 + r;
                A[row * KP + col] = f2bf(fmaxf(c1[mt][nt][r], 0.f));
            }
        }
    __syncthreads();

    // GEMM2: K=256 -> h_bf
    floatx4 c2[4][4];
    #pragma unroll
    for (int nt = 0; nt < 4; ++nt) {
        float bb = b2[ncol + nt * 16];
        #pragma unroll
        for (int mt = 0; mt < 4; ++mt) {
            c2[mt][nt][0] = bb; c2[mt][nt][1] = bb;
            c2[mt][nt][2] = bb; c2[mt][nt][3] = bb;
        }
    }
    #pragma unroll
    for (int ks = 0; ks < 8; ++ks) {
        short8 a[4], b[4];
        #pragma unroll
        for (int mt = 0; mt < 4; ++mt)
            a[mt] = *(const short8*)&A[(mt * 16 + lm) * KP + ks * 32 + quad * 8];
        #pragma unroll
        for (int nt = 0; nt < 4; ++nt)
            b[nt] = *(const short8*)&w2bt[(size_t)(ncol + nt * 16) * H + ks * 32 + quad * 8];
        #pragma unroll
        for (int mt = 0; mt < 4; ++mt)
            #pragma unroll
            for (int nt = 0; nt < 4; ++nt)
                c2[mt][nt] = __builtin_amdgcn_mfma_f32_16x16x32_bf16(a[mt], b[nt], c2[mt][nt], 0, 0, 0);
    }
    #pragma unroll
    for (int mt = 0; mt < 4; ++mt)
        #pragma unroll
        for (int r = 0; r < 4; ++r) {
            int row = mt * 16 + quad * 4 + r;
            if (row < nvalid) {
                #pragma unroll
                for (int nt = 0; nt < 4; ++nt)
                    h_bf[(size_t)(n0 + row) * H + ncol + nt * 16] = f2bf(c2[mt][nt][r]);
            }
        }
}

// ---------------------------------------------------------------------------
// Fused layer kernel: gather(h_in_bf) -> split-K GEMM (2x K=256 through one
// 64x264 LDS buffer) -> MLP -> LN. LDS ~37 KB -> 4 blocks/CU.
// ---------------------------------------------------------------------------
__global__ __launch_bounds__(256) void layer_kernel(
    const short* __restrict__ h_in_bf, short* __restrict__ h_out_bf,
    float* __restrict__ h_out_f32,
    const int* __restrict__ rs, const int* __restrict__ csr_src,
    const short* __restrict__ haggB,
    const short* __restrict__ wxwe, const float* __restrict__ be2,
    const short* __restrict__ u1bt, const float* __restrict__ b1,
    const short* __restrict__ u2bt, const float* __restrict__ b2,
    const float* __restrict__ lng, const float* __restrict__ lnb)
{
    constexpr int KP = H + 8;
    __shared__ short A[64 * KP];
    __shared__ int rsL[65];
    __shared__ float psum[64][4], psq[64][4];
    __shared__ float muS[64], rsS[64];
    const int tid  = threadIdx.x;
    const int lane = tid & 63, wave = tid >> 6;
    const int quad = lane >> 4, lm = lane & 15;
    const int n0 = blockIdx.x * 64;
    const int nvalid = min(64, N - n0);
    const int ncol = wave * 64 + lm;

    if (tid < 65) rsL[tid] = rs[min(n0 + tid, N)];
    __syncthreads();

    // --- stage 1: gather bf16 rows, f32 accumulate -> A ---
    for (int t = 0; t < 16; ++t) {
        int row = wave * 16 + t;
        int s = rsL[row], e = rsL[row + 1];
        float4 acc = {0.f, 0.f, 0.f, 0.f};
        int j = s;
        for (; j + 1 < e; j += 2) {
            int s0 = csr_src[j], s1 = csr_src[j + 1];
            sv4 v0 = *(const sv4*)&h_in_bf[(size_t)s0 * H + 4 * lane];
            sv4 v1 = *(const sv4*)&h_in_bf[(size_t)s1 * H + 4 * lane];
            acc.x += bf2f(v0.x) + bf2f(v1.x);
            acc.y += bf2f(v0.y) + bf2f(v1.y);
            acc.z += bf2f(v0.z) + bf2f(v1.z);
            acc.w += bf2f(v0.w) + bf2f(v1.w);
        }
        if (j < e) {
            int s0 = csr_src[j];
            sv4 v0 = *(const sv4*)&h_in_bf[(size_t)s0 * H + 4 * lane];
            acc.x += bf2f(v0.x); acc.y += bf2f(v0.y);
            acc.z += bf2f(v0.z); acc.w += bf2f(v0.w);
        }
        sv4 o = {f2bf(acc.x), f2bf(acc.y), f2bf(acc.z), f2bf(acc.w)};
        *(sv4*)&A[row * KP + 4 * lane] = o;
    }
    __syncthreads();

    // --- stage 2: K=512 GEMM as two K=256 passes; acc init deg*be2 ---
    floatx4 c1[4][4];
    #pragma unroll
    for (int nt = 0; nt < 4; ++nt) {
        float bb = be2[ncol + nt * 16];
        #pragma unroll
        for (int mt = 0; mt < 4; ++mt) {
            #pragma unroll
            for (int r = 0; r < 4; ++r) {
                int row = mt * 16 + quad * 4 + r;
                float deg = (float)(rsL[row + 1] - rsL[row]);
                c1[mt][nt][r] = deg * bb;
            }
        }
    }
    // pass A: cols 0..255 of wxwe (gathered hAgg in A)
    #pragma unroll
    for (int ks = 0; ks < 8; ++ks) {
        short8 a[4], b[4];
        #pragma unroll
        for (int mt = 0; mt < 4; ++mt)
            a[mt] = *(const short8*)&A[(mt * 16 + lm) * KP + ks * 32 + quad * 8];
        #pragma unroll
        for (int nt = 0; nt < 4; ++nt)
            b[nt] = *(const short8*)&wxwe[(size_t)(ncol + nt * 16) * 512 + ks * 32 + quad * 8];
        #pragma unroll
        for (int mt = 0; mt < 4; ++mt)
            #pragma unroll
            for (int nt = 0; nt < 4; ++nt)
                c1[mt][nt] = __builtin_amdgcn_mfma_f32_16x16x32_bf16(a[mt], b[nt], c1[mt][nt], 0, 0, 0);
    }
    __syncthreads();
    // reload A with hiddenAgg
    for (int i = tid; i < 64 * 64; i += 256) {
        int row = i >> 6, q = i & 63;
        sv4 v = {0, 0, 0, 0};
        if (row < nvalid)
            v = *(const sv4*)&haggB[(size_t)(n0 + row) * H + 4 * q];
        *(sv4*)&A[row * KP + 4 * q] = v;
    }
    __syncthreads();
    // pass B: cols 256..511 of wxwe (hiddenAgg in A)
    #pragma unroll
    for (int ks = 0; ks < 8; ++ks) {
        short8 a[4], b[4];
        #pragma unroll
        for (int mt = 0; mt < 4; ++mt)
            a[mt] = *(const short8*)&A[(mt * 16 + lm) * KP + ks * 32 + quad * 8];
        #pragma unroll
        for (int nt = 0; nt < 4; ++nt)
            b[nt] = *(const short8*)&wxwe[(size_t)(ncol + nt * 16) * 512 + 256 + ks * 32 + quad * 8];
        #pragma unroll
        for (int mt = 0; mt < 4; ++mt)
            #pragma unroll
            for (int nt = 0; nt < 4; ++nt)
                c1[mt][nt] = __builtin_amdgcn_mfma_f32_16x16x32_bf16(a[mt], b[nt], c1[mt][nt], 0, 0, 0);
    }
    __syncthreads();
    #pragma unroll
    for (int mt = 0; mt < 4; ++mt)
        #pragma unroll
        for (int nt = 0; nt < 4; ++nt) {
            int col = ncol + nt * 16;
            #pragma unroll
            for (int r = 0; r < 4; ++r) {
                int row = mt * 16 + quad * 4 + r;
                A[row * KP + col] = f2bf(c1[mt][nt][r]);
            }
        }
    __syncthreads();

    // --- stage 3: GEMM K=256 @W1 + b1, relu -> A ---
    floatx4 c2[4][4];
    #pragma unroll
    for (int nt = 0; nt < 4; ++nt) {
        float bb = b1[ncol + nt * 16];
        #pragma unroll
        for (int mt = 0; mt < 4; ++mt) {
            c2[mt][nt][0] = bb; c2[mt][nt][1] = bb;
            c2[mt][nt][2] = bb; c2[mt][nt][3] = bb;
        }
    }
    #pragma unroll
    for (int ks = 0; ks < 8; ++ks) {
        short8 a[4], b[4];
        #pragma unroll
        for (int mt = 0; mt < 4; ++mt)
            a[mt] = *(const short8*)&A[(mt * 16 + lm) * KP + ks * 32 + quad * 8];
        #pragma unroll
        for (int nt = 0; nt < 4; ++nt)
            b[nt] = *(const short8*)&u1bt[(size_t)(ncol + nt * 16) * H + ks * 32 + quad * 8];
        #pragma unroll
        for (int mt = 0; mt < 4; ++mt)
            #pragma unroll
            for (int nt = 0; nt < 4; ++nt)
                c2[mt][nt] = __builtin_amdgcn_mfma_f32_16x16x32_bf16(a[mt], b[nt], c2[mt][nt], 0, 0, 0);
    }
    __syncthreads();
    #pragma unroll
    for (int mt = 0; mt < 4; ++mt)
        #pragma unroll
        for (int nt = 0; nt < 4; ++nt) {
            int col = ncol + nt * 16;
            #pragma unroll
            for (int r = 0; r < 4; ++r) {
                int row = mt * 16 + quad * 4 + r;
                A[row * KP + col] = f2bf(fmaxf(c2[mt][nt][r], 0.f));
            }
        }
    __syncthreads();

    // --- stage 4: GEMM K=256 @W2 + b2 + residual; LN; store ---
    floatx4 c3[4][4];
    #pragma unroll
    for (int nt = 0; nt < 4; ++nt) {
        float bb = b2[ncol + nt * 16];
        #pragma unroll
        for (int mt = 0; mt < 4; ++mt) {
            c3[mt][nt][0] = bb; c3[mt][nt][1] = bb;
            c3[mt][nt][2] = bb; c3[mt][nt][3] = bb;
        }
    }
    #pragma unroll
    for (int ks = 0; ks < 8; ++ks) {
        short8 a[4], b[4];
        #pragma unroll
        for (int mt = 0; mt < 4; ++mt)
            a[mt] = *(const short8*)&A[(mt * 16 + lm) * KP + ks * 32 + quad * 8];
        #pragma unroll
        for (int nt = 0; nt < 4; ++nt)
            b[nt] = *(const short8*)&u2bt[(size_t)(ncol + nt * 16) * H + ks * 32 + quad * 8];
        #pragma unroll
        for (int mt = 0; mt < 4; ++mt)
            #pragma unroll
            for (int nt = 0; nt < 4; ++nt)
                c3[mt][nt] = __builtin_amdgcn_mfma_f32_16x16x32_bf16(a[mt], b[nt], c3[mt][nt], 0, 0, 0);
    }
    #pragma unroll
    for (int mt = 0; mt < 4; ++mt)
        #pragma unroll
        for (int r = 0; r < 4; ++r) {
            int row = mt * 16 + quad * 4 + r;
            if (row < nvalid) {
                #pragma unroll
                for (int nt = 0; nt < 4; ++nt)
                    c3[mt][nt][r] += bf2f(h_in_bf[(size_t)(n0 + row) * H + ncol + nt * 16]);
            }
        }

    // LN partials
    #pragma unroll
    for (int mt = 0; mt < 4; ++mt)
        #pragma unroll
        for (int r = 0; r < 4; ++r) {
            float s = 0.f, q = 0.f;
            #pragma unroll
            for (int nt = 0; nt < 4; ++nt) {
                float v = c3[mt][nt][r];
                s += v; q += v * v;
            }
            #pragma unroll
            for (int m = 1; m < 16; m <<= 1) {
                s += __shfl_xor(s, m, 64);
                q += __shfl_xor(q, m, 64);
            }
            if (lm == 0) {
                int row = mt * 16 + quad * 4 + r;
                psum[row][wave] = s;
                psq[row][wave]  = q;
            }
        }
    __syncthreads();
    if (tid < 64) {
        float s = psum[tid][0] + psum[tid][1] + psum[tid][2] + psum[tid][3];
        float q = psq[tid][0] + psq[tid][1] + psq[tid][2] + psq[tid][3];
        float mu = s * (1.f / H);
        float var = q * (1.f / H) - mu * mu;
        muS[tid] = mu;
        rsS[tid] = rsqrtf(fmaxf(var, 0.f) + 1e-5f);
    }
    __syncthreads();

    float g[4], bb4[4];
    #pragma unroll
    for (int nt = 0; nt < 4; ++nt) {
        g[nt]   = lng[ncol + nt * 16];
        bb4[nt] = lnb[ncol + nt * 16];
    }
    const bool wbf = (h_out_bf != nullptr);
    const bool wf  = (h_out_f32 != nullptr);
    #pragma unroll
    for (int mt = 0; mt < 4; ++mt)
        #pragma unroll
        for (int r = 0; r < 4; ++r) {
            int row = mt * 16 + quad * 4 + r;
            if (row < nvalid) {
                float mu = muS[row], rsv = rsS[row];
                #pragma unroll
                for (int nt = 0; nt < 4; ++nt) {
                    float o = (c3[mt][nt][r] - mu) * rsv * g[nt] + bb4[nt];
                    size_t off = (size_t)(n0 + row) * H + ncol + nt * 16;
                    if (wbf) h_out_bf[off] = f2bf(o);
                    if (wf)  h_out_f32[off] = o;
                }
            }
        }
}

// ---------------------------------------------------------------------------
// Pooling (batch sorted -> LDS accumulate, flush on change)
// ---------------------------------------------------------------------------
__global__ __launch_bounds__(256) void pool_kernel(
    const float* __restrict__ h, const int* __restrict__ batch,
    const int* __restrict__ ntype,
    float* __restrict__ zsum, float* __restrict__ zcnt)
{
    constexpr int CHUNK = 256;
    __shared__ float acc[3][H];
    __shared__ float cnt[3];
    const int tid = threadIdx.x;
    const int n0 = blockIdx.x * CHUNK;
    const int nend = min(n0 + CHUNK, N);

    for (int q = 0; q < 3; ++q) acc[q][tid] = 0.f;
    if (tid == 0) { cnt[0] = 0.f; cnt[1] = 0.f; cnt[2] = 0.f; }
    __syncthreads();

    int cur = batch[n0];
    for (int n = n0; n < nend; ++n) {
        int b = batch[n];
        int t = ntype[n];
        if (b != cur) {
            for (int q = 0; q < 3; ++q) {
                atomicAdd(&zsum[cur * (3 * H) + q * H + tid], acc[q][tid]);
                acc[q][tid] = 0.f;
            }
            if (tid == 0)
                for (int q = 0; q < 3; ++q) { atomicAdd(&zcnt[cur * 3 + q], cnt[q]); cnt[q] = 0.f; }
            cur = b;
        }
        acc[t][tid] += h[(size_t)n * H + tid];
        if (tid == 0) cnt[t] += 1.f;
    }
    for (int q = 0; q < 3; ++q)
        atomicAdd(&zsum[cur * (3 * H) + q * H + tid], acc[q][tid]);
    if (tid == 0)
        for (int q = 0; q < 3; ++q) atomicAdd(&zcnt[cur * 3 + q], cnt[q]);
}

__global__ __launch_bounds__(256) void finalize_kernel(
    const float* __restrict__ zsum, const float* __restrict__ zcnt,
    float* __restrict__ out)
{
    int idx = blockIdx.x * 256 + threadIdx.x;
    if (idx >= B * 3 * H) return;
    int b = idx / (3 * H);
    int c = idx % (3 * H);
    int t = c / H;
    float cn = zcnt[b * 3 + t];
    out[idx] = zsum[idx] / fmaxf(cn, 1.f);
}

__global__ __launch_bounds__(256) void batch_out_kernel(
    const int* __restrict__ batch, float* __restrict__ out)
{
    int idx = blockIdx.x * 256 + threadIdx.x;
    if (idx < N) out[idx] = (float)batch[idx];
}

// ---------------------------------------------------------------------------
extern "C" void kernel_launch(void* const* d_in, const int* in_sizes, int n_in,
                              void* d_out, int out_size, void* d_ws, size_t ws_size,
                              hipStream_t stream) {
    const float* x         = (const float*)d_in[0];
    const float* edge_attr = (const float*)d_in[1];
    const float* geo_w     = (const float*)d_in[2];
    const float* geo_b     = (const float*)d_in[3];
    const float* nin_w1    = (const float*)d_in[4];
    const float* nin_b1    = (const float*)d_in[5];
    const float* nin_w2    = (const float*)d_in[6];
    const float* nin_b2    = (const float*)d_in[7];
    const float* ee_w1     = (const float*)d_in[8];
    const float* ee_b1     = (const float*)d_in[9];
    const float* ee_w2     = (const float*)d_in[10];
    const float* ee_b2     = (const float*)d_in[11];
    const float* msgx_w    = (const float*)d_in[12];
    const float* msge_w    = (const float*)d_in[13];
    const float* upd_w1    = (const float*)d_in[14];
    const float* upd_b1    = (const float*)d_in[15];
    const float* upd_w2    = (const float*)d_in[16];
    const float* upd_b2    = (const float*)d_in[17];
    const float* ln_g      = (const float*)d_in[18];
    const float* ln_b      = (const float*)d_in[19];
    const int*   edge_index= (const int*)d_in[20];
    const int*   batch     = (const int*)d_in[21];
    const int*   node_type = (const int*)d_in[22];

    float* out = (float*)d_out;
    float* hf  = out + B * 3 * H;                  // final f32 h -> d_out

    // Workspace layout (~82 MB):
    short* h0_bf   = (short*)d_ws;                     // [N,H] bf16  25.6 MB
    short* h1_bf   = h0_bf + (size_t)N * H;            // [N,H] bf16  25.6 MB
    short* haggB   = h1_bf + (size_t)N * H;            // [N,H] bf16  25.6 MB
    short* wxwe    = haggB + (size_t)N * H;            // [L,H,512] bf16
    short* u1bt    = wxwe + (size_t)L * H * 512;       // [L,H,H] bf16
    short* u2bt    = u1bt + (size_t)L * H * H;         // [L,H,H] bf16
    short* geowbt  = u2bt + (size_t)L * H * H;         // [32,128]
    short* w1bt    = geowbt + 32 * 128;                // [H,64]
    short* w2bt    = w1bt + H * 64;                    // [H,H]
    float* be2     = (float*)(w2bt + H * H);           // [L,H]
    float* zsum    = be2 + L * H;                      // [B,3H]
    float* zcnt    = zsum + B * 3 * H;                 // [B,3]
    int*   rowcnt  = (int*)(zcnt + B * 3);             // [N]
    int*   rs      = rowcnt + N;                       // [N+1]
    int*   cursor  = rs + N + 1;                       // [N]
    int*   bsum    = cursor + N;                       // [256]
    int*   csr_src = bsum + 256;                       // [E]
    int*   csr_eid = csr_src + E;                      // [E]

    const int* src = edge_index;
    const int* dst = edge_index + E;

    const int nscan = (N + 255) / 256;   // 196 blocks <= 256

    // --- CSR build ---
    hipMemsetAsync(rowcnt, 0, (size_t)N * sizeof(int), stream);
    hist_kernel<<<(E + 255) / 256, 256, 0, stream>>>(dst, rowcnt);
    scan_partial_kernel<<<nscan, 256, 0, stream>>>(rowcnt, bsum);
    scan_bsum_kernel<<<1, 256, 0, stream>>>(bsum, nscan, rs + N);
    scan_final_kernel<<<nscan, 256, 0, stream>>>(rowcnt, bsum, rs, cursor);
    fill_kernel<<<(E + 255) / 256, 256, 0, stream>>>(src, dst, cursor, csr_src, csr_eid);

    // --- weight prep ---
    wx_part_kernel<<<L * 256, 256, 0, stream>>>(msgx_w, wxwe);
    we_fuse_kernel<<<L * H, 256, 0, stream>>>(ee_w2, msge_w, wxwe);
    fuse_b_kernel<<<L, 256, 0, stream>>>(ee_b2, msge_w, be2);
    conv_bt_kernel<<<L * 256, 256, 0, stream>>>(upd_w1, u1bt);
    conv_bt_kernel<<<L * 256, 256, 0, stream>>>(upd_w2, u2bt);
    conv_bt_kernel<<<256, 256, 0, stream>>>(nin_w2, w2bt);
    geow_bt_kernel<<<1, 256, 0, stream>>>(geo_w, geowbt);
    ninw1_bt_kernel<<<64, 256, 0, stream>>>(nin_w1, w1bt);

    // --- hiddenAgg (layer-independent) ---
    hidden_agg_kernel<<<(N + 15) / 16, 256, 0, stream>>>(
        edge_attr, ee_w1, ee_b1, rs, csr_eid, haggB);

    // --- node encoder -> h0_bf ---
    node_in_mfma_kernel<<<(N + 63) / 64, 256, 0, stream>>>(
        x, geowbt, geo_b, w1bt, nin_b1, w2bt, nin_b2, h0_bf);

    // --- layers: bf16 ping-pong; last layer writes f32 to d_out ---
    const int lgrid = (N + 63) / 64;
    for (int l = 0; l < L; ++l) {
        const short* hin  = (l & 1) ? h1_bf : h0_bf;
        short* hout_bf    = (l == L - 1) ? nullptr : ((l & 1) ? h0_bf : h1_bf);
        float* hout_f32   = (l == L - 1) ? hf : nullptr;
        layer_kernel<<<lgrid, 256, 0, stream>>>(
            hin, hout_bf, hout_f32, rs, csr_src, haggB,
            wxwe + (size_t)l * H * 512, be2 + (size_t)l * H,
            u1bt + (size_t)l * H * H, upd_b1 + (size_t)l * H,
            u2bt + (size_t)l * H * H, upd_b2 + (size_t)l * H,
            ln_g + (size_t)l * H, ln_b + (size_t)l * H);
    }

    // --- pooling ---
    hipMemsetAsync(zsum, 0, (size_t)(B * 3 * H + B * 3) * sizeof(float), stream);
    pool_kernel<<<(N + 255) / 256, 256, 0, stream>>>(hf, batch, node_type, zsum, zcnt);
    finalize_kernel<<<(B * 3 * H + 255) / 256, 256, 0, stream>>>(zsum, zcnt, out);
    batch_out_kernel<<<(N + 255) / 256, 256, 0, stream>>>(batch, out + B * 3 * H + (size_t)N * H);
}